// Round 11
// baseline (1458.713 us; speedup 1.0000x reference)
//
#include <hip/hip_runtime.h>
#include <hip/hip_bf16.h>

#define N_NODES 100000
#define N_EDGES 1600000
#define N_GRAPHS 512
#define NODE_DIM 64
#define GRAPH_DIM 16
#define HIDDEN 128
#define OUT_DIM 8

#define NBUCKETS 782      // ceil(N_NODES/128)
#define BNODES 128        // nodes per bucket
#define BIN_CAP 4096      // per-bucket bin capacity (avg 2046)
#define EPB 4096          // edges per binning block
#define PCHUNK 128        // pool2 chunk-blocks per channel-phase

__device__ __forceinline__ float bflo(unsigned u) { return __uint_as_float(u << 16); }
__device__ __forceinline__ float bfhi(unsigned u) { return __uint_as_float(u & 0xffff0000u); }
__device__ __forceinline__ float bf16f(ushort u) { return __uint_as_float((unsigned)u << 16); }

// ---------------- phase A: dual bin — by dst>>7 (for CSR) and by src>>7 (for pool) ----------------

__global__ __launch_bounds__(256) void k_binplace(const int* __restrict__ src,
                                                  const int* __restrict__ dst,
                                                  int* __restrict__ gcur,
                                                  unsigned* __restrict__ bin,
                                                  int* __restrict__ gcur2,
                                                  unsigned* __restrict__ bin2) {
    __shared__ int c1[NBUCKETS];
    __shared__ int b1_[NBUCKETS];
    __shared__ int c2[NBUCKETS];
    __shared__ int b2_[NBUCKETS];
    int t = threadIdx.x;
    for (int i = t; i < NBUCKETS; i += 256) { c1[i] = 0; c2[i] = 0; }
    __syncthreads();
    int e0 = blockIdx.x * EPB;
#pragma unroll
    for (int k = 0; k < EPB / 256; k++) {
        int e = e0 + k * 256 + t;
        if (e < N_EDGES) {
            atomicAdd(&c1[dst[e] >> 7], 1);
            atomicAdd(&c2[src[e] >> 7], 1);
        }
    }
    __syncthreads();
    for (int i = t; i < NBUCKETS; i += 256) {
        int c = c1[i];
        b1_[i] = (c > 0) ? atomicAdd(&gcur[i], c) : 0;
        c1[i] = 0;
        c = c2[i];
        b2_[i] = (c > 0) ? atomicAdd(&gcur2[i], c) : 0;
        c2[i] = 0;
    }
    __syncthreads();
#pragma unroll
    for (int k = 0; k < EPB / 256; k++) {
        int e = e0 + k * 256 + t;
        if (e < N_EDGES) {
            int d = dst[e], s = src[e];
            int bd = d >> 7, bs = s >> 7;
            int p1 = atomicAdd(&c1[bd], 1);
            bin[(size_t)bd * BIN_CAP + b1_[bd] + p1] = ((unsigned)s << 7) | (unsigned)(d & 127);
            int p2 = atomicAdd(&c2[bs], 1);
            bin2[(size_t)bs * BIN_CAP + b2_[bs] + p2] = ((unsigned)d << 7) | (unsigned)(s & 127);
        }
    }
}

// ---------------- phase B1: per-bucket degree count + dinv; block 0 scans gcur -> bofs ----------------

__global__ __launch_bounds__(256) void k_degscan(const int* __restrict__ gcur,
                                                 const unsigned* __restrict__ bin,
                                                 int* __restrict__ degcnt,
                                                 float* __restrict__ dinv,
                                                 int* __restrict__ bofs) {
    __shared__ int cnt[BNODES];
    int b = blockIdx.x, t = threadIdx.x;
    if (t < BNODES) cnt[t] = 0;
    __syncthreads();
    int n = gcur[b];
    const unsigned* seg = bin + (size_t)b * BIN_CAP;
    for (int i = t; i < n; i += 256) atomicAdd(&cnt[seg[i] & 127u], 1);
    __syncthreads();
    int node = b * BNODES + t;
    if (t < BNODES && node < N_NODES) {
        int c = cnt[t];
        degcnt[node] = c;
        dinv[node] = rsqrtf((float)c + 1.0f);
    }
    if (b == 0) {
        __shared__ int ls[256];
        int i0 = 4 * t;
        int c0 = (i0 + 0 < NBUCKETS) ? gcur[i0 + 0] : 0;
        int c1 = (i0 + 1 < NBUCKETS) ? gcur[i0 + 1] : 0;
        int c2 = (i0 + 2 < NBUCKETS) ? gcur[i0 + 2] : 0;
        int c3 = (i0 + 3 < NBUCKETS) ? gcur[i0 + 3] : 0;
        int s = c0 + c1 + c2 + c3;
        ls[t] = s;
        __syncthreads();
        for (int o = 1; o < 256; o <<= 1) {
            int u = (t >= o) ? ls[t - o] : 0;
            __syncthreads();
            ls[t] += u;
            __syncthreads();
        }
        int run = ls[t] - s;
        if (i0 + 0 < NBUCKETS) bofs[i0 + 0] = run; run += c0;
        if (i0 + 1 < NBUCKETS) bofs[i0 + 1] = run; run += c1;
        if (i0 + 2 < NBUCKETS) bofs[i0 + 2] = run; run += c2;
        if (i0 + 3 < NBUCKETS) bofs[i0 + 3] = run;
    }
}

// ---------------- phase B2: rowstart + dst-CSR fill (int2 {src, w}); zeroes gt_sum ----------------

__global__ __launch_bounds__(256) void k_rowfill(const int* __restrict__ degcnt,
                                                 const int* __restrict__ bofs,
                                                 const int* __restrict__ gcur,
                                                 const unsigned* __restrict__ bin,
                                                 const float* __restrict__ dinv,
                                                 int* __restrict__ row_start,
                                                 int2* __restrict__ csre,
                                                 float* __restrict__ gt_sum) {
    __shared__ int sc[BNODES];
    __shared__ int rsl[BNODES];
    __shared__ int cnt[BNODES];
    __shared__ float dl[BNODES];
    int b = blockIdx.x, t = threadIdx.x;
    if (b < 32) gt_sum[b * 256 + t] = 0.0f;
    int node = b * BNODES + t;
    int v = 0;
    if (t < BNODES) {
        v = (node < N_NODES) ? degcnt[node] : 0;
        sc[t] = v;
    }
    __syncthreads();
    for (int o = 1; o < BNODES; o <<= 1) {
        int u = 0;
        if (t < BNODES && t >= o) u = sc[t - o];
        __syncthreads();
        if (t < BNODES) sc[t] += u;
        __syncthreads();
    }
    if (t < BNODES) {
        int rs = bofs[b] + sc[t] - v;  // exclusive
        if (node < N_NODES) row_start[node] = rs;
        rsl[t] = rs;
        cnt[t] = 0;
        dl[t] = rsqrtf((float)v + 1.0f);
    }
    __syncthreads();
    int n = gcur[b];
    const unsigned* seg = bin + (size_t)b * BIN_CAP;
    for (int i = t; i < n; i += 256) {
        unsigned e = seg[i];
        int dlidx = (int)(e & 127u);
        int s = (int)(e >> 7);
        int pos = rsl[dlidx] + atomicAdd(&cnt[dlidx], 1);
        csre[pos] = make_int2(s, __float_as_int(dinv[s] * dl[dlidx]));
    }
    if (b == NBUCKETS - 1 && t == 0) row_start[N_NODES] = N_EDGES;
}

// ---------------- fused: pack x[:, :64] to bf16 + graph feature pooling ----------------

__global__ __launch_bounds__(256) void k_packstat(const float* __restrict__ x,
                                                  const int* __restrict__ batch,
                                                  ushort* __restrict__ xb,
                                                  float* __restrict__ gt_sum) {
    int t = threadIdx.x;
    int i0 = blockIdx.x * 64;
    for (int idx = t; idx < 64 * 32; idx += 256) {
        int node = i0 + (idx >> 5);
        if (node < N_NODES) {
            int c2 = idx & 31;
            float2 v = *(const float2*)&x[(size_t)node * 80 + c2 * 2];
            __hip_bfloat16 lo = __float2bfloat16(v.x);
            __hip_bfloat16 hi = __float2bfloat16(v.y);
            ushort2 pv = make_ushort2(*(ushort*)&lo, *(ushort*)&hi);
            ((ushort2*)xb)[(size_t)node * 32 + c2] = pv;
        }
    }
    int c = t & 15, sub = t >> 4;  // 16 subs x 16 channels
    int iend = min(i0 + 64, N_NODES);
    float acc = 0.0f;
    int g = -1;
    for (int i = i0 + sub; i < iend; i += 16) {
        int bi = batch[i];
        if (bi != g) {
            if (g >= 0) atomicAdd(&gt_sum[g * GRAPH_DIM + c], acc);
            acc = 0.0f; g = bi;
        }
        acc += x[(size_t)i * 80 + NODE_DIM + c];
    }
    if (g >= 0) atomicAdd(&gt_sum[g * GRAPH_DIM + c], acc);
}

// ---- fused conv1 (round-7 proven form): gather (A_hat x64) into LDS + GEMM -> h1 bf16 ----

#define LDX(s_) __uint_as_float((unsigned)xb[(size_t)(s_)*64 + lane] << 16)

__global__ __launch_bounds__(256) void k_conv1(const int2* __restrict__ csre,
                                               const int* __restrict__ row_start,
                                               const float* __restrict__ dinv,
                                               const ushort* __restrict__ xb,
                                               const float* __restrict__ W,
                                               const float* __restrict__ bias,
                                               ushort* __restrict__ C) {
    __shared__ float zs[8][64];
    int t = threadIdx.x;
    int w = t >> 6, lane = t & 63;
    int nA = blockIdx.x * 8 + w * 2;
    int nB = nA + 1;
    int kA = row_start[nA];
    int reA = row_start[nA + 1];
    int kB = reA;
    int reB = row_start[nB + 1];
    float aA0 = 0.f, aA1 = 0.f, aA2 = 0.f, aA3 = 0.f;
    float aB0 = 0.f, aB1 = 0.f, aB2 = 0.f, aB3 = 0.f;
    while (kA + 4 <= reA && kB + 4 <= reB) {
        int2 eA0 = csre[kA], eA1 = csre[kA + 1], eA2 = csre[kA + 2], eA3 = csre[kA + 3];
        int2 eB0 = csre[kB], eB1 = csre[kB + 1], eB2 = csre[kB + 2], eB3 = csre[kB + 3];
        float vA0 = LDX(eA0.x), vA1 = LDX(eA1.x), vA2 = LDX(eA2.x), vA3 = LDX(eA3.x);
        float vB0 = LDX(eB0.x), vB1 = LDX(eB1.x), vB2 = LDX(eB2.x), vB3 = LDX(eB3.x);
        aA0 += __int_as_float(eA0.y) * vA0; aA1 += __int_as_float(eA1.y) * vA1;
        aA2 += __int_as_float(eA2.y) * vA2; aA3 += __int_as_float(eA3.y) * vA3;
        aB0 += __int_as_float(eB0.y) * vB0; aB1 += __int_as_float(eB1.y) * vB1;
        aB2 += __int_as_float(eB2.y) * vB2; aB3 += __int_as_float(eB3.y) * vB3;
        kA += 4; kB += 4;
    }
    while (kA + 4 <= reA) {
        int2 e0 = csre[kA], e1 = csre[kA + 1], e2 = csre[kA + 2], e3 = csre[kA + 3];
        float v0 = LDX(e0.x), v1 = LDX(e1.x), v2 = LDX(e2.x), v3 = LDX(e3.x);
        aA0 += __int_as_float(e0.y) * v0; aA1 += __int_as_float(e1.y) * v1;
        aA2 += __int_as_float(e2.y) * v2; aA3 += __int_as_float(e3.y) * v3;
        kA += 4;
    }
    while (kB + 4 <= reB) {
        int2 e0 = csre[kB], e1 = csre[kB + 1], e2 = csre[kB + 2], e3 = csre[kB + 3];
        float v0 = LDX(e0.x), v1 = LDX(e1.x), v2 = LDX(e2.x), v3 = LDX(e3.x);
        aB0 += __int_as_float(e0.y) * v0; aB1 += __int_as_float(e1.y) * v1;
        aB2 += __int_as_float(e2.y) * v2; aB3 += __int_as_float(e3.y) * v3;
        kB += 4;
    }
    while (kA < reA && kB < reB) {
        int2 eA = csre[kA]; int2 eB = csre[kB];
        aA0 += __int_as_float(eA.y) * LDX(eA.x);
        aB0 += __int_as_float(eB.y) * LDX(eB.x);
        kA++; kB++;
    }
    while (kA < reA) { int2 e = csre[kA]; aA0 += __int_as_float(e.y) * LDX(e.x); kA++; }
    while (kB < reB) { int2 e = csre[kB]; aB0 += __int_as_float(e.y) * LDX(e.x); kB++; }
    float dA = dinv[nA], dB = dinv[nB];
    zs[w * 2][lane]     = aA0 + aA1 + aA2 + aA3 + dA * dA * LDX(nA);
    zs[w * 2 + 1][lane] = aB0 + aB1 + aB2 + aB3 + dB * dB * LDX(nB);
    __syncthreads();
    if (t < 128) {
        int j = t;
        float acc[8];
#pragma unroll
        for (int m = 0; m < 8; m++) acc[m] = 0.0f;
        for (int k = 0; k < 64; k++) {
            float wv = W[k * 128 + j];
#pragma unroll
            for (int m = 0; m < 8; m++) acc[m] += zs[m][k] * wv;
        }
        float b = bias[j];
        size_t row0 = (size_t)blockIdx.x * 8;
#pragma unroll
        for (int m = 0; m < 8; m++) {
            float v = fmaxf(acc[m] + b, 0.0f);
            __hip_bfloat16 hv = __float2bfloat16(v);
            C[(row0 + m) * 128 + j] = *(ushort*)&hv;
        }
    }
}

// ---- pool2: src-streamed pooled conv2. Each block: private LDS gsum (512 x 64ch half),
//      edges from src-buckets (h1 reads are bucket-local, L2-hot), flush to partials ----

__global__ __launch_bounds__(1024) void k_pool2(const int* __restrict__ gcur2,
                                                const unsigned* __restrict__ bin2,
                                                const float* __restrict__ dinv,
                                                const ushort* __restrict__ h1,
                                                const int* __restrict__ batch,
                                                float* __restrict__ partial) {
    __shared__ float acc[N_GRAPHS * 64];   // 128 KB
    int t = threadIdx.x;
    int wv = t >> 6, lane = t & 63;
    int phase = blockIdx.x >> 7;      // 0: ch 0..63, 1: ch 64..127
    int chunk = blockIdx.x & (PCHUNK - 1);
    for (int i = t; i < N_GRAPHS * 64; i += 1024) acc[i] = 0.0f;
    __syncthreads();
    int chbase = phase * 64;
    for (int b = chunk; b < NBUCKETS; b += PCHUNK) {
        const unsigned* seg = bin2 + (size_t)b * BIN_CAP;
        int n = gcur2[b];
        int per = (n + 15) >> 4;
        int i0 = wv * per;
        int i1 = min(i0 + per, n);
        int i = i0;
        for (; i + 2 <= i1; i += 2) {
            unsigned r0 = seg[i], r1 = seg[i + 1];
            int d0 = (int)(r0 >> 7), d1 = (int)(r1 >> 7);
            int s0 = b * 128 + (int)(r0 & 127u);
            int s1 = b * 128 + (int)(r1 & 127u);
            int g0 = batch[d0], g1 = batch[d1];
            float w0 = dinv[s0] * dinv[d0];
            float w1 = dinv[s1] * dinv[d1];
            float h0 = bf16f(h1[(size_t)s0 * 128 + chbase + lane]);
            float hv1 = bf16f(h1[(size_t)s1 * 128 + chbase + lane]);
            atomicAdd(&acc[g0 * 64 + lane], w0 * h0);
            atomicAdd(&acc[g1 * 64 + lane], w1 * hv1);
        }
        if (i < i1) {
            unsigned r0 = seg[i];
            int d0 = (int)(r0 >> 7);
            int s0 = b * 128 + (int)(r0 & 127u);
            int g0 = batch[d0];
            float w0 = dinv[s0] * dinv[d0];
            float h0 = bf16f(h1[(size_t)s0 * 128 + chbase + lane]);
            atomicAdd(&acc[g0 * 64 + lane], w0 * h0);
        }
        // self terms: 8 nodes per wave
        int nb0 = b * 128 + wv * 8;
#pragma unroll
        for (int q = 0; q < 8; q++) {
            int node = nb0 + q;
            if (node < N_NODES) {
                int g = batch[node];
                float d = dinv[node];
                float hv = bf16f(h1[(size_t)node * 128 + chbase + lane]);
                atomicAdd(&acc[g * 64 + lane], d * d * hv);
            }
        }
    }
    __syncthreads();
    float4* d4 = (float4*)(partial + (size_t)blockIdx.x * (N_GRAPHS * 64));
    const float4* s4 = (const float4*)acc;
    for (int i = t; i < N_GRAPHS * 16; i += 1024) d4[i] = s4[i];
}

// ---------------- final: partial-reduce + gcnt + z = mean2 @ W2 + b2 ; MLP ----------------

__global__ __launch_bounds__(128) void k_mlp(const float* __restrict__ partial,
                                             const float* __restrict__ gt_sum,
                                             const int* __restrict__ batch,
                                             const float* __restrict__ W2,
                                             const float* __restrict__ b2,
                                             const float* __restrict__ Wm1,
                                             const float* __restrict__ bm1,
                                             const float* __restrict__ Wm2,
                                             const float* __restrict__ bm2,
                                             float* __restrict__ out) {
    __shared__ float srow[HIDDEN];
    __shared__ float g144[HIDDEN + GRAPH_DIM];
    __shared__ float sm[HIDDEN];
    __shared__ int cnt_sh;
    int b = blockIdx.x;
    int j = threadIdx.x;  // 0..127
    // reduce the 128 per-block partials for this (graph, channel)
    int half = j >> 6, cl = j & 63;
    const float* pb = partial + (size_t)(half * PCHUNK) * (N_GRAPHS * 64) + (size_t)b * 64 + cl;
    float raw = 0.f;
#pragma unroll 4
    for (int p = 0; p < PCHUNK; p++) raw += pb[(size_t)p * (N_GRAPHS * 64)];
    float gtraw = (j < GRAPH_DIM) ? gt_sum[b * GRAPH_DIM + j] : 0.0f;
    if (j == 0) {
        int lo = 0, hi = N_NODES;
        while (lo < hi) { int m = (lo + hi) >> 1; if (batch[m] < b) lo = m + 1; else hi = m; }
        int a = lo;
        lo = 0; hi = N_NODES;
        while (lo < hi) { int m = (lo + hi) >> 1; if (batch[m] < b + 1) lo = m + 1; else hi = m; }
        cnt_sh = lo - a;
    }
    __syncthreads();
    float inv = 1.0f / fmaxf((float)cnt_sh, 1.0f);
    srow[j] = raw * inv;
    if (j < GRAPH_DIM) g144[128 + j] = gtraw * inv;
    __syncthreads();
    float z = b2[j];
    for (int k = 0; k < 128; k++) z += srow[k] * W2[k * 128 + j];
    g144[j] = z;
    __syncthreads();
    float acc = bm1[j];
    for (int k = 0; k < HIDDEN + GRAPH_DIM; k++) acc += g144[k] * Wm1[k * 128 + j];
    sm[j] = fmaxf(acc, 0.0f);
    __syncthreads();
    if (j < OUT_DIM) {
        float o = bm2[j];
        for (int k = 0; k < 128; k++) o += sm[k] * Wm2[k * OUT_DIM + j];
        out[b * OUT_DIM + j] = o;
    }
}

extern "C" void kernel_launch(void* const* d_in, const int* in_sizes, int n_in,
                              void* d_out, int out_size, void* d_ws, size_t ws_size,
                              hipStream_t stream) {
    const float* x    = (const float*)d_in[0];
    const int*   edge = (const int*)d_in[1];
    const int*   src  = edge;
    const int*   dst  = edge + N_EDGES;
    const int*   batch= (const int*)d_in[2];
    const float* W1   = (const float*)d_in[3];
    const float* b1   = (const float*)d_in[4];
    const float* W2   = (const float*)d_in[5];
    const float* b2   = (const float*)d_in[6];
    const float* Wm1  = (const float*)d_in[7];
    const float* bm1  = (const float*)d_in[8];
    const float* Wm2  = (const float*)d_in[9];
    const float* bm2  = (const float*)d_in[10];
    float* out = (float*)d_out;

    // workspace layout (~112 MB)
    char* ws = (char*)d_ws;
    char* p = ws;
    unsigned* bin   = (unsigned*)p;  p += (size_t)NBUCKETS * BIN_CAP * 4;   // 12.8 MB (dst-binned)
    unsigned* bin2  = (unsigned*)p;  p += (size_t)NBUCKETS * BIN_CAP * 4;   // 12.8 MB (src-binned)
    int2*  csre     = (int2*)p;      p += ((size_t)N_EDGES + 8) * 8;        // 12.8 MB
    ushort* h1b     = (ushort*)p;    p += (size_t)N_NODES * 128 * 2;        // 25.6 MB
    ushort* xb      = (ushort*)p;    p += (size_t)N_NODES * 64 * 2;         // 12.8 MB
    float* partial  = (float*)p;     p += (size_t)2 * PCHUNK * N_GRAPHS * 64 * 4;  // 33.5 MB
    int*   degcnt   = (int*)p;       p += (size_t)NBUCKETS * BNODES * 4;
    int*   row_start= (int*)p;       p += ((size_t)N_NODES + 1) * 4;
    float* dinv     = (float*)p;     p += (size_t)N_NODES * 4;
    int*   gcur     = (int*)p;       p += (size_t)NBUCKETS * 4;   // keep gcur, gcur2 adjacent
    int*   gcur2    = (int*)p;       p += (size_t)NBUCKETS * 4;
    int*   bofs     = (int*)p;       p += (size_t)NBUCKETS * 4;
    float* gt_sum   = (float*)p;     p += (size_t)N_GRAPHS * GRAPH_DIM * 4;

    hipMemsetAsync(gcur, 0, (size_t)NBUCKETS * 2 * 4, stream);  // gcur + gcur2

    // CSR build (dst) + src bins
    k_binplace<<<(N_EDGES + EPB - 1) / EPB, 256, 0, stream>>>(src, dst, gcur, bin, gcur2, bin2);
    k_degscan<<<NBUCKETS, 256, 0, stream>>>(gcur, bin, degcnt, dinv, bofs);
    k_rowfill<<<NBUCKETS, 256, 0, stream>>>(degcnt, bofs, gcur, bin, dinv, row_start, csre, gt_sum);

    // bf16 pack + graph stats
    k_packstat<<<(N_NODES + 63) / 64, 256, 0, stream>>>(x, batch, xb, gt_sum);

    // conv1 fused: z1 = A_hat * x64 (LDS) ; h1 = relu(z1 @ W1 + b1) (bf16)
    k_conv1<<<N_NODES / 8, 256, 0, stream>>>(csre, row_start, dinv, xb, W1, b1, h1b);

    // conv2 pooled, src-streamed: per-block LDS gsum accumulation -> partials
    k_pool2<<<2 * PCHUNK, 1024, 0, stream>>>(gcur2, bin2, dinv, h1b, batch, partial);

    // final: reduce partials + gcnt + z = (gsum/cnt) @ W2 + b2 ; MLP
    k_mlp<<<N_GRAPHS, 128, 0, stream>>>(partial, gt_sum, batch, W2, b2, Wm1, bm1, Wm2, bm2, out);
}

// Round 12
// 289.077 us; speedup vs baseline: 5.0461x; 5.0461x over previous
//
#include <hip/hip_runtime.h>
#include <hip/hip_bf16.h>

#define N_NODES 100000
#define N_EDGES 1600000
#define N_GRAPHS 512
#define NODE_DIM 64
#define GRAPH_DIM 16
#define HIDDEN 128
#define OUT_DIM 8

#define NBUCKETS 391      // ceil(N_NODES/256)
#define BIN_CAP 8192      // per-bucket bin capacity (avg 4092)
#define EPB 4096          // edges per binning block

__device__ __forceinline__ float bflo(unsigned u) { return __uint_as_float(u << 16); }
__device__ __forceinline__ float bfhi(unsigned u) { return __uint_as_float(u & 0xffff0000u); }

// ---------------- phase A: bin edges by dst>>8; entry = (src<<8)|(dst&255) ----------------

__global__ __launch_bounds__(256) void k_binplace(const int* __restrict__ src,
                                                  const int* __restrict__ dst,
                                                  int* __restrict__ gcur,
                                                  unsigned* __restrict__ bin) {
    __shared__ int cnt[NBUCKETS];
    __shared__ int base[NBUCKETS];
    int t = threadIdx.x;
    for (int i = t; i < NBUCKETS; i += 256) cnt[i] = 0;
    __syncthreads();
    int e0 = blockIdx.x * EPB;
#pragma unroll
    for (int k = 0; k < EPB / 256; k++) {
        int e = e0 + k * 256 + t;
        if (e < N_EDGES) atomicAdd(&cnt[dst[e] >> 8], 1);
    }
    __syncthreads();
    for (int i = t; i < NBUCKETS; i += 256) {
        int c = cnt[i];
        base[i] = (c > 0) ? atomicAdd(&gcur[i], c) : 0;
        cnt[i] = 0;
    }
    __syncthreads();
#pragma unroll
    for (int k = 0; k < EPB / 256; k++) {
        int e = e0 + k * 256 + t;
        if (e < N_EDGES) {
            int d = dst[e];
            int b = d >> 8;
            int p = atomicAdd(&cnt[b], 1);
            bin[(size_t)b * BIN_CAP + base[b] + p] = ((unsigned)src[e] << 8) | (unsigned)(d & 255);
        }
    }
}

// ---------------- phase B1: per-bucket degree count + dinv + block sum ----------------

__global__ __launch_bounds__(256) void k_degBf(const int* __restrict__ gcur,
                                               const unsigned* __restrict__ bin,
                                               int* __restrict__ degcnt,
                                               float* __restrict__ dinv,
                                               int* __restrict__ bsum) {
    __shared__ int cnt[256];
    int b = blockIdx.x, t = threadIdx.x;
    cnt[t] = 0;
    __syncthreads();
    int n = gcur[b];
    const unsigned* seg = bin + (size_t)b * BIN_CAP;
    for (int i = t; i < n; i += 256) atomicAdd(&cnt[seg[i] & 255u], 1);
    __syncthreads();
    int c = cnt[t];
    int node = b * 256 + t;
    if (node < N_NODES) {
        degcnt[node] = c;
        dinv[node] = rsqrtf((float)c + 1.0f);
    }
    __syncthreads();
    for (int o = 128; o > 0; o >>= 1) {
        if (t < o) cnt[t] += cnt[t + o];
        __syncthreads();
    }
    if (t == 0) bsum[b] = cnt[0];
}

// ---------------- exclusive scan of bsum -> bofs (one 512-thread block) ----------------

__global__ __launch_bounds__(512) void k_scanb(const int* __restrict__ bsum,
                                               int* __restrict__ bofs) {
    __shared__ int s[512];
    int t = threadIdx.x;
    int v = (t < NBUCKETS) ? bsum[t] : 0;
    s[t] = v;
    __syncthreads();
    for (int o = 1; o < 512; o <<= 1) {
        int u = (t >= o) ? s[t - o] : 0;
        __syncthreads();
        s[t] += u;
        __syncthreads();
    }
    if (t < NBUCKETS) bofs[t] = s[t] - v;
}

// ---------------- phase B2: fused rowstart + CSR fill (int2 {src, w}); zeroes gt_sum ----------------

__global__ __launch_bounds__(256) void k_rowfill(const int* __restrict__ degcnt,
                                                 const int* __restrict__ bofs,
                                                 const int* __restrict__ gcur,
                                                 const unsigned* __restrict__ bin,
                                                 const float* __restrict__ dinv,
                                                 int* __restrict__ row_start,
                                                 int2* __restrict__ csre,
                                                 float* __restrict__ gt_sum) {
    __shared__ int sc[256];
    __shared__ int rsl[256];
    __shared__ int cnt[256];
    __shared__ float dl[256];
    int b = blockIdx.x, t = threadIdx.x;
    if (b < 32) gt_sum[b * 256 + t] = 0.0f;
    int node = b * 256 + t;
    int v = (node < N_NODES) ? degcnt[node] : 0;
    sc[t] = v;
    __syncthreads();
    for (int o = 1; o < 256; o <<= 1) {
        int u = (t >= o) ? sc[t - o] : 0;
        __syncthreads();
        sc[t] += u;
        __syncthreads();
    }
    int rs = bofs[b] + sc[t] - v;  // exclusive
    if (node < N_NODES) row_start[node] = rs;
    rsl[t] = rs;
    cnt[t] = 0;
    dl[t] = rsqrtf((float)v + 1.0f);
    __syncthreads();
    int n = gcur[b];
    const unsigned* seg = bin + (size_t)b * BIN_CAP;
    for (int i = t; i < n; i += 256) {
        unsigned e = seg[i];
        int dlidx = (int)(e & 255u);
        int s = (int)(e >> 8);
        int pos = rsl[dlidx] + atomicAdd(&cnt[dlidx], 1);
        csre[pos] = make_int2(s, __float_as_int(dinv[s] * dl[dlidx]));
    }
}

// ---------------- fused: pack x[:, :64] to bf16 + graph feature pooling ----------------

__global__ __launch_bounds__(256) void k_packstat(const float* __restrict__ x,
                                                  const int* __restrict__ batch,
                                                  ushort* __restrict__ xb,
                                                  float* __restrict__ gt_sum) {
    int t = threadIdx.x;
    int i0 = blockIdx.x * 64;
    for (int idx = t; idx < 64 * 32; idx += 256) {
        int node = i0 + (idx >> 5);
        if (node < N_NODES) {
            int c2 = idx & 31;
            float2 v = *(const float2*)&x[(size_t)node * 80 + c2 * 2];
            __hip_bfloat16 lo = __float2bfloat16(v.x);
            __hip_bfloat16 hi = __float2bfloat16(v.y);
            ushort2 pv = make_ushort2(*(ushort*)&lo, *(ushort*)&hi);
            ((ushort2*)xb)[(size_t)node * 32 + c2] = pv;
        }
    }
    int c = t & 15, sub = t >> 4;  // 16 subs x 16 channels
    int iend = min(i0 + 64, N_NODES);
    float acc = 0.0f;
    int g = -1;
    for (int i = i0 + sub; i < iend; i += 16) {
        int bi = batch[i];
        if (bi != g) {
            if (g >= 0) atomicAdd(&gt_sum[g * GRAPH_DIM + c], acc);
            acc = 0.0f; g = bi;
        }
        acc += x[(size_t)i * 80 + NODE_DIM + c];
    }
    if (g >= 0) atomicAdd(&gt_sum[g * GRAPH_DIM + c], acc);
}

// ---- fused conv1: gather (A_hat x64) into LDS + GEMM -> h1 bf16 PLANES; zeroes gsum2 ----

#define LDX(s_) __uint_as_float((unsigned)xb[(size_t)(s_)*64 + lane] << 16)

__global__ __launch_bounds__(256) void k_conv1(const int2* __restrict__ csre,
                                               const int* __restrict__ row_start,
                                               const float* __restrict__ dinv,
                                               const ushort* __restrict__ xb,
                                               const float* __restrict__ W,
                                               const float* __restrict__ bias,
                                               ushort* __restrict__ C,   // 2 planes of N_NODES*64
                                               float* __restrict__ gsum2) {
    __shared__ float zs[8][64];
    int t = threadIdx.x;
    if (blockIdx.x < 256) gsum2[blockIdx.x * 256 + t] = 0.0f;
    int w = t >> 6, lane = t & 63;
    int nA = blockIdx.x * 8 + w * 2;
    int nB = nA + 1;
    int kA = row_start[nA];
    int reA = (nA == N_NODES - 1) ? N_EDGES : row_start[nA + 1];
    int kB = reA;
    int reB = (nB == N_NODES - 1) ? N_EDGES : row_start[nB + 1];
    float aA0 = 0.f, aA1 = 0.f, aA2 = 0.f, aA3 = 0.f;
    float aB0 = 0.f, aB1 = 0.f, aB2 = 0.f, aB3 = 0.f;
    while (kA + 4 <= reA && kB + 4 <= reB) {
        int2 eA0 = csre[kA], eA1 = csre[kA + 1], eA2 = csre[kA + 2], eA3 = csre[kA + 3];
        int2 eB0 = csre[kB], eB1 = csre[kB + 1], eB2 = csre[kB + 2], eB3 = csre[kB + 3];
        float vA0 = LDX(eA0.x), vA1 = LDX(eA1.x), vA2 = LDX(eA2.x), vA3 = LDX(eA3.x);
        float vB0 = LDX(eB0.x), vB1 = LDX(eB1.x), vB2 = LDX(eB2.x), vB3 = LDX(eB3.x);
        aA0 += __int_as_float(eA0.y) * vA0; aA1 += __int_as_float(eA1.y) * vA1;
        aA2 += __int_as_float(eA2.y) * vA2; aA3 += __int_as_float(eA3.y) * vA3;
        aB0 += __int_as_float(eB0.y) * vB0; aB1 += __int_as_float(eB1.y) * vB1;
        aB2 += __int_as_float(eB2.y) * vB2; aB3 += __int_as_float(eB3.y) * vB3;
        kA += 4; kB += 4;
    }
    while (kA + 4 <= reA) {
        int2 e0 = csre[kA], e1 = csre[kA + 1], e2 = csre[kA + 2], e3 = csre[kA + 3];
        float v0 = LDX(e0.x), v1 = LDX(e1.x), v2 = LDX(e2.x), v3 = LDX(e3.x);
        aA0 += __int_as_float(e0.y) * v0; aA1 += __int_as_float(e1.y) * v1;
        aA2 += __int_as_float(e2.y) * v2; aA3 += __int_as_float(e3.y) * v3;
        kA += 4;
    }
    while (kB + 4 <= reB) {
        int2 e0 = csre[kB], e1 = csre[kB + 1], e2 = csre[kB + 2], e3 = csre[kB + 3];
        float v0 = LDX(e0.x), v1 = LDX(e1.x), v2 = LDX(e2.x), v3 = LDX(e3.x);
        aB0 += __int_as_float(e0.y) * v0; aB1 += __int_as_float(e1.y) * v1;
        aB2 += __int_as_float(e2.y) * v2; aB3 += __int_as_float(e3.y) * v3;
        kB += 4;
    }
    while (kA < reA && kB < reB) {
        int2 eA = csre[kA]; int2 eB = csre[kB];
        aA0 += __int_as_float(eA.y) * LDX(eA.x);
        aB0 += __int_as_float(eB.y) * LDX(eB.x);
        kA++; kB++;
    }
    while (kA < reA) { int2 e = csre[kA]; aA0 += __int_as_float(e.y) * LDX(e.x); kA++; }
    while (kB < reB) { int2 e = csre[kB]; aB0 += __int_as_float(e.y) * LDX(e.x); kB++; }
    float dA = dinv[nA], dB = dinv[nB];
    zs[w * 2][lane]     = aA0 + aA1 + aA2 + aA3 + dA * dA * LDX(nA);
    zs[w * 2 + 1][lane] = aB0 + aB1 + aB2 + aB3 + dB * dB * LDX(nB);
    __syncthreads();
    if (t < 128) {
        int j = t;
        float acc[8];
#pragma unroll
        for (int m = 0; m < 8; m++) acc[m] = 0.0f;
        for (int k = 0; k < 64; k++) {
            float wv = W[k * 128 + j];
#pragma unroll
            for (int m = 0; m < 8; m++) acc[m] += zs[m][k] * wv;
        }
        float b = bias[j];
        size_t row0 = (size_t)blockIdx.x * 8;
        // plane layout: ch<64 -> plane0[node*64+ch], ch>=64 -> plane1[node*64+ch-64]
        ushort* Cp = C + ((j >> 6) ? (size_t)N_NODES * 64 : 0);
        int jc = j & 63;
#pragma unroll
        for (int m = 0; m < 8; m++) {
            float v = fmaxf(acc[m] + b, 0.0f);
            __hip_bfloat16 hv = __float2bfloat16(v);
            Cp[(row0 + m) * 64 + jc] = *(ushort*)&hv;
        }
    }
}

// ---- gather2s: channel-split conv2+pool. phase=(bid&7)>>2 pins plane per XCD (bid%8≈XCD).
//      Each wave: 2 nodes, lane = channel within plane (ushort loads, 128B/edge). ----

#define LDH(s_) __uint_as_float((unsigned)hp[(size_t)(s_)*64 + lane] << 16)

__global__ __launch_bounds__(256) void k_gather2s(const int2* __restrict__ csre,
                                                  const int* __restrict__ row_start,
                                                  const float* __restrict__ dinv,
                                                  const ushort* __restrict__ h1planes,
                                                  const int* __restrict__ batch,
                                                  float* __restrict__ gsum2) {
    __shared__ float red[8][64];
    int b = blockIdx.x;
    int r = b & 7;
    int phase = r >> 2;                  // XCDs 0-3 -> plane0, 4-7 -> plane1
    int nb = (b >> 3) * 4 + (r & 3);     // 0..12499 per phase
    const ushort* hp = h1planes + (size_t)phase * N_NODES * 64;
    int w = threadIdx.x >> 6, lane = threadIdx.x & 63;
    int nA = nb * 8 + w * 2;
    int nB = nA + 1;
    int kA = row_start[nA];
    int reA = (nA == N_NODES - 1) ? N_EDGES : row_start[nA + 1];
    int kB = reA;
    int reB = (nB == N_NODES - 1) ? N_EDGES : row_start[nB + 1];
    float aA0 = 0.f, aA1 = 0.f, aA2 = 0.f, aA3 = 0.f;
    float aB0 = 0.f, aB1 = 0.f, aB2 = 0.f, aB3 = 0.f;
    while (kA + 4 <= reA && kB + 4 <= reB) {
        int2 eA0 = csre[kA], eA1 = csre[kA + 1], eA2 = csre[kA + 2], eA3 = csre[kA + 3];
        int2 eB0 = csre[kB], eB1 = csre[kB + 1], eB2 = csre[kB + 2], eB3 = csre[kB + 3];
        float vA0 = LDH(eA0.x), vA1 = LDH(eA1.x), vA2 = LDH(eA2.x), vA3 = LDH(eA3.x);
        float vB0 = LDH(eB0.x), vB1 = LDH(eB1.x), vB2 = LDH(eB2.x), vB3 = LDH(eB3.x);
        aA0 += __int_as_float(eA0.y) * vA0; aA1 += __int_as_float(eA1.y) * vA1;
        aA2 += __int_as_float(eA2.y) * vA2; aA3 += __int_as_float(eA3.y) * vA3;
        aB0 += __int_as_float(eB0.y) * vB0; aB1 += __int_as_float(eB1.y) * vB1;
        aB2 += __int_as_float(eB2.y) * vB2; aB3 += __int_as_float(eB3.y) * vB3;
        kA += 4; kB += 4;
    }
    while (kA + 4 <= reA) {
        int2 e0 = csre[kA], e1 = csre[kA + 1], e2 = csre[kA + 2], e3 = csre[kA + 3];
        float v0 = LDH(e0.x), v1 = LDH(e1.x), v2 = LDH(e2.x), v3 = LDH(e3.x);
        aA0 += __int_as_float(e0.y) * v0; aA1 += __int_as_float(e1.y) * v1;
        aA2 += __int_as_float(e2.y) * v2; aA3 += __int_as_float(e3.y) * v3;
        kA += 4;
    }
    while (kB + 4 <= reB) {
        int2 e0 = csre[kB], e1 = csre[kB + 1], e2 = csre[kB + 2], e3 = csre[kB + 3];
        float v0 = LDH(e0.x), v1 = LDH(e1.x), v2 = LDH(e2.x), v3 = LDH(e3.x);
        aB0 += __int_as_float(e0.y) * v0; aB1 += __int_as_float(e1.y) * v1;
        aB2 += __int_as_float(e2.y) * v2; aB3 += __int_as_float(e3.y) * v3;
        kB += 4;
    }
    while (kA < reA && kB < reB) {
        int2 eA = csre[kA]; int2 eB = csre[kB];
        aA0 += __int_as_float(eA.y) * LDH(eA.x);
        aB0 += __int_as_float(eB.y) * LDH(eB.x);
        kA++; kB++;
    }
    while (kA < reA) { int2 e = csre[kA]; aA0 += __int_as_float(e.y) * LDH(e.x); kA++; }
    while (kB < reB) { int2 e = csre[kB]; aB0 += __int_as_float(e.y) * LDH(e.x); kB++; }
    float dA = dinv[nA], dB = dinv[nB];
    float rA = aA0 + aA1 + aA2 + aA3 + dA * dA * LDH(nA);
    float rB = aB0 + aB1 + aB2 + aB3 + dB * dB * LDH(nB);
    red[w * 2][lane] = rA;
    red[w * 2 + 1][lane] = rB;
    __syncthreads();
    int g0 = batch[nb * 8];
    int g7 = batch[nb * 8 + 7];
    int chofs = phase * 64 + lane;
    if (g0 == g7) {
        if (w == 0) {
            float s = 0.f;
#pragma unroll
            for (int q = 0; q < 8; q++) s += red[q][lane];
            atomicAdd(&gsum2[g0 * 128 + chofs], s);
        }
    } else {
        int gA = batch[nA], gB = batch[nB];
        atomicAdd(&gsum2[gA * 128 + chofs], rA);
        atomicAdd(&gsum2[gB * 128 + chofs], rB);
    }
}

// ---------------- final: gcnt (binary search) + z = mean2 @ W2 + b2 ; MLP ----------------

__global__ __launch_bounds__(128) void k_mlp(const float* __restrict__ gsum2,
                                             const float* __restrict__ gt_sum,
                                             const int* __restrict__ batch,
                                             const float* __restrict__ W2,
                                             const float* __restrict__ b2,
                                             const float* __restrict__ Wm1,
                                             const float* __restrict__ bm1,
                                             const float* __restrict__ Wm2,
                                             const float* __restrict__ bm2,
                                             float* __restrict__ out) {
    __shared__ float srow[HIDDEN];
    __shared__ float g144[HIDDEN + GRAPH_DIM];
    __shared__ float sm[HIDDEN];
    __shared__ int cnt_sh;
    int b = blockIdx.x;
    int j = threadIdx.x;  // 0..127
    float raw = gsum2[b * 128 + j];
    float gtraw = (j < GRAPH_DIM) ? gt_sum[b * GRAPH_DIM + j] : 0.0f;
    if (j == 0) {
        int lo = 0, hi = N_NODES;
        while (lo < hi) { int m = (lo + hi) >> 1; if (batch[m] < b) lo = m + 1; else hi = m; }
        int a = lo;
        lo = 0; hi = N_NODES;
        while (lo < hi) { int m = (lo + hi) >> 1; if (batch[m] < b + 1) lo = m + 1; else hi = m; }
        cnt_sh = lo - a;
    }
    __syncthreads();
    float inv = 1.0f / fmaxf((float)cnt_sh, 1.0f);
    srow[j] = raw * inv;
    if (j < GRAPH_DIM) g144[128 + j] = gtraw * inv;
    __syncthreads();
    float z = b2[j];
    for (int k = 0; k < 128; k++) z += srow[k] * W2[k * 128 + j];
    g144[j] = z;
    __syncthreads();
    float acc = bm1[j];
    for (int k = 0; k < HIDDEN + GRAPH_DIM; k++) acc += g144[k] * Wm1[k * 128 + j];
    sm[j] = fmaxf(acc, 0.0f);
    __syncthreads();
    if (j < OUT_DIM) {
        float o = bm2[j];
        for (int k = 0; k < 128; k++) o += sm[k] * Wm2[k * OUT_DIM + j];
        out[b * OUT_DIM + j] = o;
    }
}

extern "C" void kernel_launch(void* const* d_in, const int* in_sizes, int n_in,
                              void* d_out, int out_size, void* d_ws, size_t ws_size,
                              hipStream_t stream) {
    const float* x    = (const float*)d_in[0];
    const int*   edge = (const int*)d_in[1];
    const int*   src  = edge;
    const int*   dst  = edge + N_EDGES;
    const int*   batch= (const int*)d_in[2];
    const float* W1   = (const float*)d_in[3];
    const float* b1   = (const float*)d_in[4];
    const float* W2   = (const float*)d_in[5];
    const float* b2   = (const float*)d_in[6];
    const float* Wm1  = (const float*)d_in[7];
    const float* bm1  = (const float*)d_in[8];
    const float* Wm2  = (const float*)d_in[9];
    const float* bm2  = (const float*)d_in[10];
    float* out = (float*)d_out;

    // workspace layout (~66 MB)
    char* ws = (char*)d_ws;
    char* p = ws;
    unsigned* bin   = (unsigned*)p;  p += (size_t)NBUCKETS * BIN_CAP * 4;   // 12.8 MB
    int2*  csre     = (int2*)p;      p += ((size_t)N_EDGES + 8) * 8;        // 12.8 MB
    ushort* h1b     = (ushort*)p;    p += (size_t)N_NODES * 128 * 2;        // 25.6 MB (2 planes)
    ushort* xb      = (ushort*)p;    p += (size_t)N_NODES * 64 * 2;         // 12.8 MB
    int*   degcnt   = (int*)p;       p += (size_t)NBUCKETS * 256 * 4;
    int*   row_start= (int*)p;       p += ((size_t)N_NODES + 1) * 4;
    float* dinv     = (float*)p;     p += (size_t)N_NODES * 4;
    int*   gcur     = (int*)p;       p += (size_t)NBUCKETS * 4;
    int*   bsum     = (int*)p;       p += 512 * 4;
    int*   bofs     = (int*)p;       p += 512 * 4;
    float* gt_sum   = (float*)p;     p += (size_t)N_GRAPHS * GRAPH_DIM * 4;
    float* gsum2    = (float*)p;     p += (size_t)N_GRAPHS * 128 * 4;

    hipMemsetAsync(gcur, 0, (size_t)NBUCKETS * 4, stream);

    // CSR build
    k_binplace<<<(N_EDGES + EPB - 1) / EPB, 256, 0, stream>>>(src, dst, gcur, bin);
    k_degBf<<<NBUCKETS, 256, 0, stream>>>(gcur, bin, degcnt, dinv, bsum);
    k_scanb<<<1, 512, 0, stream>>>(bsum, bofs);
    k_rowfill<<<NBUCKETS, 256, 0, stream>>>(degcnt, bofs, gcur, bin, dinv, row_start, csre, gt_sum);

    // bf16 pack + graph stats
    k_packstat<<<(N_NODES + 63) / 64, 256, 0, stream>>>(x, batch, xb, gt_sum);

    // conv1 fused: z1 = A_hat * x64 (LDS) ; h1 = relu(z1 @ W1 + b1) (bf16, plane layout)
    k_conv1<<<N_NODES / 8, 256, 0, stream>>>(csre, row_start, dinv, xb, W1, b1, h1b, gsum2);

    // conv2 pooled, channel-split by XCD: gsum2[g] = sum_{node in g} (A_hat h1)[node]
    k_gather2s<<<25000, 256, 0, stream>>>(csre, row_start, dinv, h1b, batch, gsum2);

    // final: gcnt + z = (gsum2/cnt) @ W2 + b2 ; MLP
    k_mlp<<<N_GRAPHS, 128, 0, stream>>>(gsum2, gt_sum, batch, W2, b2, Wm1, bm1, Wm2, bm2, out);
}

// Round 13
// 237.725 us; speedup vs baseline: 6.1361x; 1.2160x over previous
//
#include <hip/hip_runtime.h>
#include <hip/hip_bf16.h>

#define N_NODES 100000
#define N_EDGES 1600000
#define N_GRAPHS 512
#define NODE_DIM 64
#define GRAPH_DIM 16
#define HIDDEN 128
#define OUT_DIM 8

#define NBUCKETS 391      // ceil(N_NODES/256)
#define BIN_CAP 8192      // per-bucket bin + csr capacity (avg 4092)
#define EPB 4096          // edges per binning block

__device__ __forceinline__ float bflo(unsigned u) { return __uint_as_float(u << 16); }
__device__ __forceinline__ float bfhi(unsigned u) { return __uint_as_float(u & 0xffff0000u); }

// ---------------- phase A: bin edges by dst>>8; entry = (src<<8)|(dst&255) ----------------

__global__ __launch_bounds__(256) void k_binplace(const int* __restrict__ src,
                                                  const int* __restrict__ dst,
                                                  int* __restrict__ gcur,
                                                  unsigned* __restrict__ bin) {
    __shared__ int cnt[NBUCKETS];
    __shared__ int base[NBUCKETS];
    int t = threadIdx.x;
    for (int i = t; i < NBUCKETS; i += 256) cnt[i] = 0;
    __syncthreads();
    int e0 = blockIdx.x * EPB;
#pragma unroll
    for (int k = 0; k < EPB / 256; k++) {
        int e = e0 + k * 256 + t;
        if (e < N_EDGES) atomicAdd(&cnt[dst[e] >> 8], 1);
    }
    __syncthreads();
    for (int i = t; i < NBUCKETS; i += 256) {
        int c = cnt[i];
        base[i] = (c > 0) ? atomicAdd(&gcur[i], c) : 0;
        cnt[i] = 0;
    }
    __syncthreads();
#pragma unroll
    for (int k = 0; k < EPB / 256; k++) {
        int e = e0 + k * 256 + t;
        if (e < N_EDGES) {
            int d = dst[e];
            int b = d >> 8;
            int p = atomicAdd(&cnt[b], 1);
            bin[(size_t)b * BIN_CAP + base[b] + p] = ((unsigned)src[e] << 8) | (unsigned)(d & 255);
        }
    }
}

// ---- phase B (fused): per-bucket count -> dinv + rowse -> place src into bucket-region CSR ----

__global__ __launch_bounds__(256) void k_build(const int* __restrict__ gcur,
                                               const unsigned* __restrict__ bin,
                                               float* __restrict__ dinv,
                                               int2* __restrict__ rowse,
                                               int* __restrict__ csr,
                                               float* __restrict__ gt_sum) {
    __shared__ int cnt[256];
    __shared__ int sc[256];
    __shared__ int rsl[256];
    int b = blockIdx.x, t = threadIdx.x;
    if (b < 32) gt_sum[b * 256 + t] = 0.0f;   // fused zeroing of gt_sum (8192 floats)
    cnt[t] = 0;
    __syncthreads();
    int n = gcur[b];
    const unsigned* seg = bin + (size_t)b * BIN_CAP;
    for (int i = t; i < n; i += 256) atomicAdd(&cnt[seg[i] & 255u], 1);
    __syncthreads();
    int deg = cnt[t];
    sc[t] = deg;
    __syncthreads();
    for (int o = 1; o < 256; o <<= 1) {
        int u = (t >= o) ? sc[t - o] : 0;
        __syncthreads();
        sc[t] += u;
        __syncthreads();
    }
    int rs = b * BIN_CAP + sc[t] - deg;   // bucket-region base, exclusive prefix
    int node = b * 256 + t;
    if (node < N_NODES) {
        dinv[node] = rsqrtf((float)deg + 1.0f);
        rowse[node] = make_int2(rs, rs + deg);
    }
    rsl[t] = rs;
    cnt[t] = 0;
    __syncthreads();
    for (int i = t; i < n; i += 256) {
        unsigned e = seg[i];
        int dlidx = (int)(e & 255u);
        csr[rsl[dlidx] + atomicAdd(&cnt[dlidx], 1)] = (int)(e >> 8);
    }
}

// ---------------- fused: pack x[:, :64] to bf16 + graph feature pooling ----------------

__global__ __launch_bounds__(256) void k_packstat(const float* __restrict__ x,
                                                  const int* __restrict__ batch,
                                                  ushort* __restrict__ xb,
                                                  float* __restrict__ gt_sum) {
    int t = threadIdx.x;
    int i0 = blockIdx.x * 64;
    for (int idx = t; idx < 64 * 32; idx += 256) {
        int node = i0 + (idx >> 5);
        if (node < N_NODES) {
            int c2 = idx & 31;
            float2 v = *(const float2*)&x[(size_t)node * 80 + c2 * 2];
            __hip_bfloat16 lo = __float2bfloat16(v.x);
            __hip_bfloat16 hi = __float2bfloat16(v.y);
            ushort2 pv = make_ushort2(*(ushort*)&lo, *(ushort*)&hi);
            ((ushort2*)xb)[(size_t)node * 32 + c2] = pv;
        }
    }
    int c = t & 15, sub = t >> 4;  // 16 subs x 16 channels
    int iend = min(i0 + 64, N_NODES);
    float acc = 0.0f;
    int g = -1;
    for (int i = i0 + sub; i < iend; i += 16) {
        int bi = batch[i];
        if (bi != g) {
            if (g >= 0) atomicAdd(&gt_sum[g * GRAPH_DIM + c], acc);
            acc = 0.0f; g = bi;
        }
        acc += x[(size_t)i * 80 + NODE_DIM + c];
    }
    if (g >= 0) atomicAdd(&gt_sum[g * GRAPH_DIM + c], acc);
}

// ---- fused conv1: gather (A_hat x64) into LDS + full-block GEMM -> h1 bf16; zeroes gsum2 ----

#define LDX(s_) __uint_as_float((unsigned)xb[(size_t)(s_)*64 + lane] << 16)

__global__ __launch_bounds__(256) void k_conv1(const int* __restrict__ csr,
                                               const int2* __restrict__ rowse,
                                               const float* __restrict__ dinv,
                                               const ushort* __restrict__ xb,
                                               const float* __restrict__ W,
                                               const float* __restrict__ bias,
                                               ushort* __restrict__ C,
                                               float* __restrict__ gsum2) {
    __shared__ float zs[8][64];
    int t = threadIdx.x;
    if (blockIdx.x < 256) gsum2[blockIdx.x * 256 + t] = 0.0f;
    int w = t >> 6, lane = t & 63;
    int nA = blockIdx.x * 8 + w * 2;
    int nB = nA + 1;
    int2 seA = rowse[nA];
    int2 seB = rowse[nB];
    int kA = seA.x, reA = seA.y;
    int kB = seB.x, reB = seB.y;
    float dA = dinv[nA], dB = dinv[nB];
    float aA0 = 0.f, aA1 = 0.f, aA2 = 0.f, aA3 = 0.f;
    float aB0 = 0.f, aB1 = 0.f, aB2 = 0.f, aB3 = 0.f;
    while (kA + 4 <= reA && kB + 4 <= reB) {
        int a0 = csr[kA], a1 = csr[kA + 1], a2 = csr[kA + 2], a3 = csr[kA + 3];
        int b0 = csr[kB], b1 = csr[kB + 1], b2 = csr[kB + 2], b3 = csr[kB + 3];
        float wa0 = dinv[a0] * dA, wa1 = dinv[a1] * dA, wa2 = dinv[a2] * dA, wa3 = dinv[a3] * dA;
        float wb0 = dinv[b0] * dB, wb1 = dinv[b1] * dB, wb2 = dinv[b2] * dB, wb3 = dinv[b3] * dB;
        float vA0 = LDX(a0), vA1 = LDX(a1), vA2 = LDX(a2), vA3 = LDX(a3);
        float vB0 = LDX(b0), vB1 = LDX(b1), vB2 = LDX(b2), vB3 = LDX(b3);
        aA0 += wa0 * vA0; aA1 += wa1 * vA1; aA2 += wa2 * vA2; aA3 += wa3 * vA3;
        aB0 += wb0 * vB0; aB1 += wb1 * vB1; aB2 += wb2 * vB2; aB3 += wb3 * vB3;
        kA += 4; kB += 4;
    }
    while (kA + 4 <= reA) {
        int a0 = csr[kA], a1 = csr[kA + 1], a2 = csr[kA + 2], a3 = csr[kA + 3];
        float wa0 = dinv[a0] * dA, wa1 = dinv[a1] * dA, wa2 = dinv[a2] * dA, wa3 = dinv[a3] * dA;
        float v0 = LDX(a0), v1 = LDX(a1), v2 = LDX(a2), v3 = LDX(a3);
        aA0 += wa0 * v0; aA1 += wa1 * v1; aA2 += wa2 * v2; aA3 += wa3 * v3;
        kA += 4;
    }
    while (kB + 4 <= reB) {
        int b0 = csr[kB], b1 = csr[kB + 1], b2 = csr[kB + 2], b3 = csr[kB + 3];
        float wb0 = dinv[b0] * dB, wb1 = dinv[b1] * dB, wb2 = dinv[b2] * dB, wb3 = dinv[b3] * dB;
        float v0 = LDX(b0), v1 = LDX(b1), v2 = LDX(b2), v3 = LDX(b3);
        aB0 += wb0 * v0; aB1 += wb1 * v1; aB2 += wb2 * v2; aB3 += wb3 * v3;
        kB += 4;
    }
    while (kA < reA && kB < reB) {
        int a0 = csr[kA]; int b0 = csr[kB];
        aA0 += dinv[a0] * dA * LDX(a0);
        aB0 += dinv[b0] * dB * LDX(b0);
        kA++; kB++;
    }
    while (kA < reA) { int a0 = csr[kA]; aA0 += dinv[a0] * dA * LDX(a0); kA++; }
    while (kB < reB) { int b0 = csr[kB]; aB0 += dinv[b0] * dB * LDX(b0); kB++; }
    zs[w * 2][lane]     = aA0 + aA1 + aA2 + aA3 + dA * dA * LDX(nA);
    zs[w * 2 + 1][lane] = aB0 + aB1 + aB2 + aB3 + dB * dB * LDX(nB);
    __syncthreads();
    // GEMM phase: all 256 threads; j = t&127, half hf computes rows hf*4 .. hf*4+3
    {
        int j = t & 127;
        int hf = t >> 7;
        float acc[4];
#pragma unroll
        for (int m = 0; m < 4; m++) acc[m] = 0.0f;
        for (int k = 0; k < 64; k++) {
            float wk = W[k * 128 + j];
#pragma unroll
            for (int m = 0; m < 4; m++) acc[m] += zs[hf * 4 + m][k] * wk;
        }
        float b = bias[j];
        size_t row0 = (size_t)blockIdx.x * 8 + hf * 4;
#pragma unroll
        for (int m = 0; m < 4; m++) {
            float v = fmaxf(acc[m] + b, 0.0f);
            __hip_bfloat16 hv = __float2bfloat16(v);
            C[(row0 + m) * 128 + j] = *(ushort*)&hv;
        }
    }
}

// ---- gather2 (bf16 h1, whole-wave, 2 nodes/wave, 2ch/lane) + fused mean-pool ----

__global__ __launch_bounds__(256) void k_gather2(const int* __restrict__ csr,
                                                 const int2* __restrict__ rowse,
                                                 const float* __restrict__ dinv,
                                                 const unsigned* __restrict__ h,
                                                 const int* __restrict__ batch,
                                                 float* __restrict__ gsum2) {
    __shared__ float2 red[8][64];
    int w = threadIdx.x >> 6, lane = threadIdx.x & 63;
    int nA = blockIdx.x * 8 + w * 2;
    int nB = nA + 1;
    int2 seA = rowse[nA];
    int2 seB = rowse[nB];
    int kA = seA.x, reA = seA.y;
    int kB = seB.x, reB = seB.y;
    float dA = dinv[nA], dB = dinv[nB];
    float2 aA0 = {0.f,0.f}, aA1 = {0.f,0.f}, aA2 = {0.f,0.f}, aA3 = {0.f,0.f};
    float2 aB0 = {0.f,0.f}, aB1 = {0.f,0.f}, aB2 = {0.f,0.f}, aB3 = {0.f,0.f};
#define FMA2(acc_, w_, u_) { acc_.x += (w_) * bflo(u_); acc_.y += (w_) * bfhi(u_); }
    while (kA + 4 <= reA && kB + 4 <= reB) {
        int a0 = csr[kA], a1 = csr[kA + 1], a2 = csr[kA + 2], a3 = csr[kA + 3];
        int b0 = csr[kB], b1 = csr[kB + 1], b2 = csr[kB + 2], b3 = csr[kB + 3];
        float wa0 = dinv[a0] * dA, wa1 = dinv[a1] * dA, wa2 = dinv[a2] * dA, wa3 = dinv[a3] * dA;
        float wb0 = dinv[b0] * dB, wb1 = dinv[b1] * dB, wb2 = dinv[b2] * dB, wb3 = dinv[b3] * dB;
        unsigned uA0 = h[(size_t)a0 * 64 + lane], uA1 = h[(size_t)a1 * 64 + lane];
        unsigned uA2 = h[(size_t)a2 * 64 + lane], uA3 = h[(size_t)a3 * 64 + lane];
        unsigned uB0 = h[(size_t)b0 * 64 + lane], uB1 = h[(size_t)b1 * 64 + lane];
        unsigned uB2 = h[(size_t)b2 * 64 + lane], uB3 = h[(size_t)b3 * 64 + lane];
        FMA2(aA0, wa0, uA0); FMA2(aA1, wa1, uA1); FMA2(aA2, wa2, uA2); FMA2(aA3, wa3, uA3);
        FMA2(aB0, wb0, uB0); FMA2(aB1, wb1, uB1); FMA2(aB2, wb2, uB2); FMA2(aB3, wb3, uB3);
        kA += 4; kB += 4;
    }
    while (kA + 4 <= reA) {
        int a0 = csr[kA], a1 = csr[kA + 1], a2 = csr[kA + 2], a3 = csr[kA + 3];
        float wa0 = dinv[a0] * dA, wa1 = dinv[a1] * dA, wa2 = dinv[a2] * dA, wa3 = dinv[a3] * dA;
        unsigned u0 = h[(size_t)a0 * 64 + lane], u1 = h[(size_t)a1 * 64 + lane];
        unsigned u2 = h[(size_t)a2 * 64 + lane], u3 = h[(size_t)a3 * 64 + lane];
        FMA2(aA0, wa0, u0); FMA2(aA1, wa1, u1); FMA2(aA2, wa2, u2); FMA2(aA3, wa3, u3);
        kA += 4;
    }
    while (kB + 4 <= reB) {
        int b0 = csr[kB], b1 = csr[kB + 1], b2 = csr[kB + 2], b3 = csr[kB + 3];
        float wb0 = dinv[b0] * dB, wb1 = dinv[b1] * dB, wb2 = dinv[b2] * dB, wb3 = dinv[b3] * dB;
        unsigned u0 = h[(size_t)b0 * 64 + lane], u1 = h[(size_t)b1 * 64 + lane];
        unsigned u2 = h[(size_t)b2 * 64 + lane], u3 = h[(size_t)b3 * 64 + lane];
        FMA2(aB0, wb0, u0); FMA2(aB1, wb1, u1); FMA2(aB2, wb2, u2); FMA2(aB3, wb3, u3);
        kB += 4;
    }
    while (kA < reA && kB < reB) {
        int a0 = csr[kA]; int b0 = csr[kB];
        float wa0 = dinv[a0] * dA, wb0 = dinv[b0] * dB;
        unsigned uA = h[(size_t)a0 * 64 + lane], uB = h[(size_t)b0 * 64 + lane];
        FMA2(aA0, wa0, uA); FMA2(aB0, wb0, uB);
        kA++; kB++;
    }
    while (kA < reA) {
        int a0 = csr[kA];
        unsigned u = h[(size_t)a0 * 64 + lane];
        FMA2(aA0, dinv[a0] * dA, u); kA++;
    }
    while (kB < reB) {
        int b0 = csr[kB];
        unsigned u = h[(size_t)b0 * 64 + lane];
        FMA2(aB0, dinv[b0] * dB, u); kB++;
    }
#undef FMA2
    unsigned usA = h[(size_t)nA * 64 + lane];
    unsigned usB = h[(size_t)nB * 64 + lane];
    float2 rA, rB;
    rA.x = aA0.x + aA1.x + aA2.x + aA3.x + dA * dA * bflo(usA);
    rA.y = aA0.y + aA1.y + aA2.y + aA3.y + dA * dA * bfhi(usA);
    rB.x = aB0.x + aB1.x + aB2.x + aB3.x + dB * dB * bflo(usB);
    rB.y = aB0.y + aB1.y + aB2.y + aB3.y + dB * dB * bfhi(usB);
    red[w * 2][lane] = rA;
    red[w * 2 + 1][lane] = rB;
    __syncthreads();
    int g0 = batch[blockIdx.x * 8];
    int g7 = batch[blockIdx.x * 8 + 7];
    if (g0 == g7) {
        if (w == 0) {
            float sx = 0.f, sy = 0.f;
#pragma unroll
            for (int q = 0; q < 8; q++) { sx += red[q][lane].x; sy += red[q][lane].y; }
            atomicAdd(&gsum2[g0 * 128 + 2 * lane], sx);
            atomicAdd(&gsum2[g0 * 128 + 2 * lane + 1], sy);
        }
    } else {
        int gA = batch[nA], gB = batch[nB];
        atomicAdd(&gsum2[gA * 128 + 2 * lane], rA.x);
        atomicAdd(&gsum2[gA * 128 + 2 * lane + 1], rA.y);
        atomicAdd(&gsum2[gB * 128 + 2 * lane], rB.x);
        atomicAdd(&gsum2[gB * 128 + 2 * lane + 1], rB.y);
    }
}

// ---------------- final: gcnt (binary search) + z = mean2 @ W2 + b2 ; MLP ----------------

__global__ __launch_bounds__(128) void k_mlp(const float* __restrict__ gsum2,
                                             const float* __restrict__ gt_sum,
                                             const int* __restrict__ batch,
                                             const float* __restrict__ W2,
                                             const float* __restrict__ b2,
                                             const float* __restrict__ Wm1,
                                             const float* __restrict__ bm1,
                                             const float* __restrict__ Wm2,
                                             const float* __restrict__ bm2,
                                             float* __restrict__ out) {
    __shared__ float srow[HIDDEN];
    __shared__ float g144[HIDDEN + GRAPH_DIM];
    __shared__ float sm[HIDDEN];
    __shared__ int cnt_sh;
    int b = blockIdx.x;
    int j = threadIdx.x;  // 0..127
    float raw = gsum2[b * 128 + j];
    float gtraw = (j < GRAPH_DIM) ? gt_sum[b * GRAPH_DIM + j] : 0.0f;
    if (j == 0) {
        int lo = 0, hi = N_NODES;
        while (lo < hi) { int m = (lo + hi) >> 1; if (batch[m] < b) lo = m + 1; else hi = m; }
        int a = lo;
        lo = 0; hi = N_NODES;
        while (lo < hi) { int m = (lo + hi) >> 1; if (batch[m] < b + 1) lo = m + 1; else hi = m; }
        cnt_sh = lo - a;
    }
    __syncthreads();
    float inv = 1.0f / fmaxf((float)cnt_sh, 1.0f);
    srow[j] = raw * inv;
    if (j < GRAPH_DIM) g144[128 + j] = gtraw * inv;
    __syncthreads();
    float z = b2[j];
    for (int k = 0; k < 128; k++) z += srow[k] * W2[k * 128 + j];
    g144[j] = z;
    __syncthreads();
    float acc = bm1[j];
    for (int k = 0; k < HIDDEN + GRAPH_DIM; k++) acc += g144[k] * Wm1[k * 128 + j];
    sm[j] = fmaxf(acc, 0.0f);
    __syncthreads();
    if (j < OUT_DIM) {
        float o = bm2[j];
        for (int k = 0; k < 128; k++) o += sm[k] * Wm2[k * OUT_DIM + j];
        out[b * OUT_DIM + j] = o;
    }
}

extern "C" void kernel_launch(void* const* d_in, const int* in_sizes, int n_in,
                              void* d_out, int out_size, void* d_ws, size_t ws_size,
                              hipStream_t stream) {
    const float* x    = (const float*)d_in[0];
    const int*   edge = (const int*)d_in[1];
    const int*   src  = edge;
    const int*   dst  = edge + N_EDGES;
    const int*   batch= (const int*)d_in[2];
    const float* W1   = (const float*)d_in[3];
    const float* b1   = (const float*)d_in[4];
    const float* W2   = (const float*)d_in[5];
    const float* b2   = (const float*)d_in[6];
    const float* Wm1  = (const float*)d_in[7];
    const float* bm1  = (const float*)d_in[8];
    const float* Wm2  = (const float*)d_in[9];
    const float* bm2  = (const float*)d_in[10];
    float* out = (float*)d_out;

    // workspace layout (~66 MB)
    char* ws = (char*)d_ws;
    char* p = ws;
    unsigned* bin   = (unsigned*)p;  p += (size_t)NBUCKETS * BIN_CAP * 4;   // 12.8 MB
    int*   csr      = (int*)p;       p += (size_t)NBUCKETS * BIN_CAP * 4;   // 12.8 MB (bucket regions)
    ushort* h1b     = (ushort*)p;    p += (size_t)N_NODES * 128 * 2;        // 25.6 MB
    ushort* xb      = (ushort*)p;    p += (size_t)N_NODES * 64 * 2;         // 12.8 MB
    int2*  rowse    = (int2*)p;      p += (size_t)N_NODES * 8;              // 800 KB
    float* dinv     = (float*)p;     p += (size_t)N_NODES * 4;
    int*   gcur     = (int*)p;       p += (size_t)NBUCKETS * 4;
    float* gt_sum   = (float*)p;     p += (size_t)N_GRAPHS * GRAPH_DIM * 4;
    float* gsum2    = (float*)p;     p += (size_t)N_GRAPHS * 128 * 4;

    hipMemsetAsync(gcur, 0, (size_t)NBUCKETS * 4, stream);

    // CSR build: bin, then fused count+scan+fill per bucket
    k_binplace<<<(N_EDGES + EPB - 1) / EPB, 256, 0, stream>>>(src, dst, gcur, bin);
    k_build<<<NBUCKETS, 256, 0, stream>>>(gcur, bin, dinv, rowse, csr, gt_sum);

    // bf16 pack + graph stats
    k_packstat<<<(N_NODES + 63) / 64, 256, 0, stream>>>(x, batch, xb, gt_sum);

    // conv1 fused: z1 = A_hat * x64 (LDS) ; h1 = relu(z1 @ W1 + b1) (bf16)
    k_conv1<<<N_NODES / 8, 256, 0, stream>>>(csr, rowse, dinv, xb, W1, b1, h1b, gsum2);

    // conv2 pooled: gsum2[g] = sum_{node in g} (A_hat h1)[node]
    k_gather2<<<N_NODES / 8, 256, 0, stream>>>(csr, rowse, dinv,
                                               (const unsigned*)h1b, batch, gsum2);

    // final: gcnt + z = (gsum2/cnt) @ W2 + b2 ; MLP
    k_mlp<<<N_GRAPHS, 128, 0, stream>>>(gsum2, gt_sum, batch, W2, b2, Wm1, bm1, Wm2, bm2, out);
}

// Round 14
// 236.167 us; speedup vs baseline: 6.1766x; 1.0066x over previous
//
#include <hip/hip_runtime.h>
#include <hip/hip_bf16.h>

#define N_NODES 100000
#define N_EDGES 1600000
#define N_GRAPHS 512
#define NODE_DIM 64
#define GRAPH_DIM 16
#define HIDDEN 128
#define OUT_DIM 8

#define NBUCKETS 391      // ceil(N_NODES/256)
#define BIN_CAP 8192      // per-bucket bin + csr capacity (avg 4092)
#define EPB 4096          // edges per binning block
#define NB_BIN 391        // binplace blocks = ceil(N_EDGES/EPB)
#define NB_PACK 1563      // packstat blocks = ceil(N_NODES/64)

__device__ __forceinline__ float bflo(unsigned u) { return __uint_as_float(u << 16); }
__device__ __forceinline__ float bfhi(unsigned u) { return __uint_as_float(u & 0xffff0000u); }

// ---- merged phase A: blocks [0,NB_BIN) bin edges by dst>>8; blocks [NB_BIN,..) pack x + graph stats ----

__global__ __launch_bounds__(256) void k_binpack(const int* __restrict__ src,
                                                 const int* __restrict__ dst,
                                                 int* __restrict__ gcur,
                                                 unsigned* __restrict__ bin,
                                                 const float* __restrict__ x,
                                                 const int* __restrict__ batch,
                                                 ushort* __restrict__ xb,
                                                 float* __restrict__ gt_sum) {
    int t = threadIdx.x;
    if (blockIdx.x < NB_BIN) {
        __shared__ int cnt[NBUCKETS];
        __shared__ int base[NBUCKETS];
        for (int i = t; i < NBUCKETS; i += 256) cnt[i] = 0;
        __syncthreads();
        int e0 = blockIdx.x * EPB;
#pragma unroll
        for (int k = 0; k < EPB / 256; k++) {
            int e = e0 + k * 256 + t;
            if (e < N_EDGES) atomicAdd(&cnt[dst[e] >> 8], 1);
        }
        __syncthreads();
        for (int i = t; i < NBUCKETS; i += 256) {
            int c = cnt[i];
            base[i] = (c > 0) ? atomicAdd(&gcur[i], c) : 0;
            cnt[i] = 0;
        }
        __syncthreads();
#pragma unroll
        for (int k = 0; k < EPB / 256; k++) {
            int e = e0 + k * 256 + t;
            if (e < N_EDGES) {
                int d = dst[e];
                int b = d >> 8;
                int p = atomicAdd(&cnt[b], 1);
                bin[(size_t)b * BIN_CAP + base[b] + p] = ((unsigned)src[e] << 8) | (unsigned)(d & 255);
            }
        }
    } else {
        int i0 = (blockIdx.x - NB_BIN) * 64;
        for (int idx = t; idx < 64 * 32; idx += 256) {
            int node = i0 + (idx >> 5);
            if (node < N_NODES) {
                int c2 = idx & 31;
                float2 v = *(const float2*)&x[(size_t)node * 80 + c2 * 2];
                __hip_bfloat16 lo = __float2bfloat16(v.x);
                __hip_bfloat16 hi = __float2bfloat16(v.y);
                ushort2 pv = make_ushort2(*(ushort*)&lo, *(ushort*)&hi);
                ((ushort2*)xb)[(size_t)node * 32 + c2] = pv;
            }
        }
        int c = t & 15, sub = t >> 4;  // 16 subs x 16 channels
        int iend = min(i0 + 64, N_NODES);
        float acc = 0.0f;
        int g = -1;
        for (int i = i0 + sub; i < iend; i += 16) {
            int bi = batch[i];
            if (bi != g) {
                if (g >= 0) atomicAdd(&gt_sum[g * GRAPH_DIM + c], acc);
                acc = 0.0f; g = bi;
            }
            acc += x[(size_t)i * 80 + NODE_DIM + c];
        }
        if (g >= 0) atomicAdd(&gt_sum[g * GRAPH_DIM + c], acc);
    }
}

// ---- phase B (fused): per-bucket count -> dinv + rowse -> place src into bucket-region CSR ----

__global__ __launch_bounds__(256) void k_build(const int* __restrict__ gcur,
                                               const unsigned* __restrict__ bin,
                                               float* __restrict__ dinv,
                                               int2* __restrict__ rowse,
                                               int* __restrict__ csr) {
    __shared__ int cnt[256];
    __shared__ int sc[256];
    __shared__ int rsl[256];
    int b = blockIdx.x, t = threadIdx.x;
    cnt[t] = 0;
    __syncthreads();
    int n = gcur[b];
    const unsigned* seg = bin + (size_t)b * BIN_CAP;
    for (int i = t; i < n; i += 256) atomicAdd(&cnt[seg[i] & 255u], 1);
    __syncthreads();
    int deg = cnt[t];
    sc[t] = deg;
    __syncthreads();
    for (int o = 1; o < 256; o <<= 1) {
        int u = (t >= o) ? sc[t - o] : 0;
        __syncthreads();
        sc[t] += u;
        __syncthreads();
    }
    int rs = b * BIN_CAP + sc[t] - deg;   // bucket-region base, exclusive prefix
    int node = b * 256 + t;
    if (node < N_NODES) {
        dinv[node] = rsqrtf((float)deg + 1.0f);
        rowse[node] = make_int2(rs, rs + deg);
    }
    rsl[t] = rs;
    cnt[t] = 0;
    __syncthreads();
    for (int i = t; i < n; i += 256) {
        unsigned e = seg[i];
        int dlidx = (int)(e & 255u);
        csr[rsl[dlidx] + atomicAdd(&cnt[dlidx], 1)] = (int)(e >> 8);
    }
}

// ---- fused conv1: unroll-8 cascade gather (A_hat x64) into LDS + full-block GEMM; zeroes gsum2 ----

#define LDX(s_) __uint_as_float((unsigned)xb[(size_t)(s_)*64 + lane] << 16)

#define C1_E8(kX, dX, aX0, aX1, aX2, aX3) {                                          \
    int s0 = csr[kX],     s1 = csr[kX + 1], s2 = csr[kX + 2], s3 = csr[kX + 3];      \
    int s4 = csr[kX + 4], s5 = csr[kX + 5], s6 = csr[kX + 6], s7 = csr[kX + 7];      \
    float w0 = dinv[s0] * dX, w1 = dinv[s1] * dX, w2 = dinv[s2] * dX, w3 = dinv[s3] * dX; \
    float w4 = dinv[s4] * dX, w5 = dinv[s5] * dX, w6 = dinv[s6] * dX, w7 = dinv[s7] * dX; \
    float v0 = LDX(s0), v1 = LDX(s1), v2 = LDX(s2), v3 = LDX(s3);                    \
    float v4 = LDX(s4), v5 = LDX(s5), v6 = LDX(s6), v7 = LDX(s7);                    \
    aX0 += w0 * v0; aX1 += w1 * v1; aX2 += w2 * v2; aX3 += w3 * v3;                  \
    aX0 += w4 * v4; aX1 += w5 * v5; aX2 += w6 * v6; aX3 += w7 * v7; }

#define C1_E4(kX, dX, aX0, aX1, aX2, aX3) {                                          \
    int s0 = csr[kX], s1 = csr[kX + 1], s2 = csr[kX + 2], s3 = csr[kX + 3];          \
    float w0 = dinv[s0] * dX, w1 = dinv[s1] * dX, w2 = dinv[s2] * dX, w3 = dinv[s3] * dX; \
    float v0 = LDX(s0), v1 = LDX(s1), v2 = LDX(s2), v3 = LDX(s3);                    \
    aX0 += w0 * v0; aX1 += w1 * v1; aX2 += w2 * v2; aX3 += w3 * v3; }

#define C1_E1(kX, dX, aX0) {                                                         \
    int s0 = csr[kX];                                                                \
    aX0 += dinv[s0] * dX * LDX(s0); }

__global__ __launch_bounds__(256) void k_conv1(const int* __restrict__ csr,
                                               const int2* __restrict__ rowse,
                                               const float* __restrict__ dinv,
                                               const ushort* __restrict__ xb,
                                               const float* __restrict__ W,
                                               const float* __restrict__ bias,
                                               ushort* __restrict__ C,
                                               float* __restrict__ gsum2) {
    __shared__ float zs[8][64];
    int t = threadIdx.x;
    if (blockIdx.x < 256) gsum2[blockIdx.x * 256 + t] = 0.0f;
    int w = t >> 6, lane = t & 63;
    int nA = blockIdx.x * 8 + w * 2;
    int nB = nA + 1;
    int2 seA = rowse[nA];
    int2 seB = rowse[nB];
    int kA = seA.x, reA = seA.y;
    int kB = seB.x, reB = seB.y;
    float dA = dinv[nA], dB = dinv[nB];
    float aA0 = 0.f, aA1 = 0.f, aA2 = 0.f, aA3 = 0.f;
    float aB0 = 0.f, aB1 = 0.f, aB2 = 0.f, aB3 = 0.f;
    while (kA + 8 <= reA && kB + 8 <= reB) {
        C1_E8(kA, dA, aA0, aA1, aA2, aA3)
        C1_E8(kB, dB, aB0, aB1, aB2, aB3)
        kA += 8; kB += 8;
    }
    while (kA + 8 <= reA) { C1_E8(kA, dA, aA0, aA1, aA2, aA3) kA += 8; }
    while (kB + 8 <= reB) { C1_E8(kB, dB, aB0, aB1, aB2, aB3) kB += 8; }
    while (kA + 4 <= reA && kB + 4 <= reB) {
        C1_E4(kA, dA, aA0, aA1, aA2, aA3)
        C1_E4(kB, dB, aB0, aB1, aB2, aB3)
        kA += 4; kB += 4;
    }
    while (kA + 4 <= reA) { C1_E4(kA, dA, aA0, aA1, aA2, aA3) kA += 4; }
    while (kB + 4 <= reB) { C1_E4(kB, dB, aB0, aB1, aB2, aB3) kB += 4; }
    while (kA < reA && kB < reB) { C1_E1(kA, dA, aA0) C1_E1(kB, dB, aB0) kA++; kB++; }
    while (kA < reA) { C1_E1(kA, dA, aA0) kA++; }
    while (kB < reB) { C1_E1(kB, dB, aB0) kB++; }
    zs[w * 2][lane]     = aA0 + aA1 + aA2 + aA3 + dA * dA * LDX(nA);
    zs[w * 2 + 1][lane] = aB0 + aB1 + aB2 + aB3 + dB * dB * LDX(nB);
    __syncthreads();
    // GEMM phase: all 256 threads; j = t&127, half hf computes rows hf*4 .. hf*4+3
    {
        int j = t & 127;
        int hf = t >> 7;
        float acc[4];
#pragma unroll
        for (int m = 0; m < 4; m++) acc[m] = 0.0f;
        for (int k = 0; k < 64; k++) {
            float wk = W[k * 128 + j];
#pragma unroll
            for (int m = 0; m < 4; m++) acc[m] += zs[hf * 4 + m][k] * wk;
        }
        float b = bias[j];
        size_t row0 = (size_t)blockIdx.x * 8 + hf * 4;
#pragma unroll
        for (int m = 0; m < 4; m++) {
            float v = fmaxf(acc[m] + b, 0.0f);
            __hip_bfloat16 hv = __float2bfloat16(v);
            C[(row0 + m) * 128 + j] = *(ushort*)&hv;
        }
    }
}

// ---- gather2: unroll-8 cascade (bf16 h1, whole-wave, 2 nodes/wave, 2ch/lane) + fused mean-pool ----

#define FMA2(acc_, w_, u_) { acc_.x += (w_) * bflo(u_); acc_.y += (w_) * bfhi(u_); }

#define G2_E8(kX, dX, aX0, aX1, aX2, aX3) {                                          \
    int s0 = csr[kX],     s1 = csr[kX + 1], s2 = csr[kX + 2], s3 = csr[kX + 3];      \
    int s4 = csr[kX + 4], s5 = csr[kX + 5], s6 = csr[kX + 6], s7 = csr[kX + 7];      \
    float w0 = dinv[s0] * dX, w1 = dinv[s1] * dX, w2 = dinv[s2] * dX, w3 = dinv[s3] * dX; \
    float w4 = dinv[s4] * dX, w5 = dinv[s5] * dX, w6 = dinv[s6] * dX, w7 = dinv[s7] * dX; \
    unsigned u0 = h[(size_t)s0 * 64 + lane], u1 = h[(size_t)s1 * 64 + lane];         \
    unsigned u2 = h[(size_t)s2 * 64 + lane], u3 = h[(size_t)s3 * 64 + lane];         \
    unsigned u4 = h[(size_t)s4 * 64 + lane], u5 = h[(size_t)s5 * 64 + lane];         \
    unsigned u6 = h[(size_t)s6 * 64 + lane], u7 = h[(size_t)s7 * 64 + lane];         \
    FMA2(aX0, w0, u0) FMA2(aX1, w1, u1) FMA2(aX2, w2, u2) FMA2(aX3, w3, u3)          \
    FMA2(aX0, w4, u4) FMA2(aX1, w5, u5) FMA2(aX2, w6, u6) FMA2(aX3, w7, u7) }

#define G2_E4(kX, dX, aX0, aX1, aX2, aX3) {                                          \
    int s0 = csr[kX], s1 = csr[kX + 1], s2 = csr[kX + 2], s3 = csr[kX + 3];          \
    float w0 = dinv[s0] * dX, w1 = dinv[s1] * dX, w2 = dinv[s2] * dX, w3 = dinv[s3] * dX; \
    unsigned u0 = h[(size_t)s0 * 64 + lane], u1 = h[(size_t)s1 * 64 + lane];         \
    unsigned u2 = h[(size_t)s2 * 64 + lane], u3 = h[(size_t)s3 * 64 + lane];         \
    FMA2(aX0, w0, u0) FMA2(aX1, w1, u1) FMA2(aX2, w2, u2) FMA2(aX3, w3, u3) }

#define G2_E1(kX, dX, aX0) {                                                         \
    int s0 = csr[kX];                                                                \
    unsigned u0 = h[(size_t)s0 * 64 + lane];                                         \
    FMA2(aX0, dinv[s0] * dX, u0) }

__global__ __launch_bounds__(256) void k_gather2(const int* __restrict__ csr,
                                                 const int2* __restrict__ rowse,
                                                 const float* __restrict__ dinv,
                                                 const unsigned* __restrict__ h,
                                                 const int* __restrict__ batch,
                                                 float* __restrict__ gsum2) {
    __shared__ float2 red[8][64];
    int w = threadIdx.x >> 6, lane = threadIdx.x & 63;
    int nA = blockIdx.x * 8 + w * 2;
    int nB = nA + 1;
    int2 seA = rowse[nA];
    int2 seB = rowse[nB];
    int kA = seA.x, reA = seA.y;
    int kB = seB.x, reB = seB.y;
    float dA = dinv[nA], dB = dinv[nB];
    float2 aA0 = {0.f,0.f}, aA1 = {0.f,0.f}, aA2 = {0.f,0.f}, aA3 = {0.f,0.f};
    float2 aB0 = {0.f,0.f}, aB1 = {0.f,0.f}, aB2 = {0.f,0.f}, aB3 = {0.f,0.f};
    while (kA + 8 <= reA && kB + 8 <= reB) {
        G2_E8(kA, dA, aA0, aA1, aA2, aA3)
        G2_E8(kB, dB, aB0, aB1, aB2, aB3)
        kA += 8; kB += 8;
    }
    while (kA + 8 <= reA) { G2_E8(kA, dA, aA0, aA1, aA2, aA3) kA += 8; }
    while (kB + 8 <= reB) { G2_E8(kB, dB, aB0, aB1, aB2, aB3) kB += 8; }
    while (kA + 4 <= reA && kB + 4 <= reB) {
        G2_E4(kA, dA, aA0, aA1, aA2, aA3)
        G2_E4(kB, dB, aB0, aB1, aB2, aB3)
        kA += 4; kB += 4;
    }
    while (kA + 4 <= reA) { G2_E4(kA, dA, aA0, aA1, aA2, aA3) kA += 4; }
    while (kB + 4 <= reB) { G2_E4(kB, dB, aB0, aB1, aB2, aB3) kB += 4; }
    while (kA < reA && kB < reB) { G2_E1(kA, dA, aA0) G2_E1(kB, dB, aB0) kA++; kB++; }
    while (kA < reA) { G2_E1(kA, dA, aA0) kA++; }
    while (kB < reB) { G2_E1(kB, dB, aB0) kB++; }
    unsigned usA = h[(size_t)nA * 64 + lane];
    unsigned usB = h[(size_t)nB * 64 + lane];
    float2 rA, rB;
    rA.x = aA0.x + aA1.x + aA2.x + aA3.x + dA * dA * bflo(usA);
    rA.y = aA0.y + aA1.y + aA2.y + aA3.y + dA * dA * bfhi(usA);
    rB.x = aB0.x + aB1.x + aB2.x + aB3.x + dB * dB * bflo(usB);
    rB.y = aB0.y + aB1.y + aB2.y + aB3.y + dB * dB * bfhi(usB);
    red[w * 2][lane] = rA;
    red[w * 2 + 1][lane] = rB;
    __syncthreads();
    int g0 = batch[blockIdx.x * 8];
    int g7 = batch[blockIdx.x * 8 + 7];
    if (g0 == g7) {
        if (w == 0) {
            float sx = 0.f, sy = 0.f;
#pragma unroll
            for (int q = 0; q < 8; q++) { sx += red[q][lane].x; sy += red[q][lane].y; }
            atomicAdd(&gsum2[g0 * 128 + 2 * lane], sx);
            atomicAdd(&gsum2[g0 * 128 + 2 * lane + 1], sy);
        }
    } else {
        int gA = batch[nA], gB = batch[nB];
        atomicAdd(&gsum2[gA * 128 + 2 * lane], rA.x);
        atomicAdd(&gsum2[gA * 128 + 2 * lane + 1], rA.y);
        atomicAdd(&gsum2[gB * 128 + 2 * lane], rB.x);
        atomicAdd(&gsum2[gB * 128 + 2 * lane + 1], rB.y);
    }
}

// ---------------- final: gcnt (binary search) + z = mean2 @ W2 + b2 ; MLP ----------------

__global__ __launch_bounds__(128) void k_mlp(const float* __restrict__ gsum2,
                                             const float* __restrict__ gt_sum,
                                             const int* __restrict__ batch,
                                             const float* __restrict__ W2,
                                             const float* __restrict__ b2,
                                             const float* __restrict__ Wm1,
                                             const float* __restrict__ bm1,
                                             const float* __restrict__ Wm2,
                                             const float* __restrict__ bm2,
                                             float* __restrict__ out) {
    __shared__ float srow[HIDDEN];
    __shared__ float g144[HIDDEN + GRAPH_DIM];
    __shared__ float sm[HIDDEN];
    __shared__ int cnt_sh;
    int b = blockIdx.x;
    int j = threadIdx.x;  // 0..127
    float raw = gsum2[b * 128 + j];
    float gtraw = (j < GRAPH_DIM) ? gt_sum[b * GRAPH_DIM + j] : 0.0f;
    if (j == 0) {
        int lo = 0, hi = N_NODES;
        while (lo < hi) { int m = (lo + hi) >> 1; if (batch[m] < b) lo = m + 1; else hi = m; }
        int a = lo;
        lo = 0; hi = N_NODES;
        while (lo < hi) { int m = (lo + hi) >> 1; if (batch[m] < b + 1) lo = m + 1; else hi = m; }
        cnt_sh = lo - a;
    }
    __syncthreads();
    float inv = 1.0f / fmaxf((float)cnt_sh, 1.0f);
    srow[j] = raw * inv;
    if (j < GRAPH_DIM) g144[128 + j] = gtraw * inv;
    __syncthreads();
    float z = b2[j];
    for (int k = 0; k < 128; k++) z += srow[k] * W2[k * 128 + j];
    g144[j] = z;
    __syncthreads();
    float acc = bm1[j];
    for (int k = 0; k < HIDDEN + GRAPH_DIM; k++) acc += g144[k] * Wm1[k * 128 + j];
    sm[j] = fmaxf(acc, 0.0f);
    __syncthreads();
    if (j < OUT_DIM) {
        float o = bm2[j];
        for (int k = 0; k < 128; k++) o += sm[k] * Wm2[k * OUT_DIM + j];
        out[b * OUT_DIM + j] = o;
    }
}

extern "C" void kernel_launch(void* const* d_in, const int* in_sizes, int n_in,
                              void* d_out, int out_size, void* d_ws, size_t ws_size,
                              hipStream_t stream) {
    const float* x    = (const float*)d_in[0];
    const int*   edge = (const int*)d_in[1];
    const int*   src  = edge;
    const int*   dst  = edge + N_EDGES;
    const int*   batch= (const int*)d_in[2];
    const float* W1   = (const float*)d_in[3];
    const float* b1   = (const float*)d_in[4];
    const float* W2   = (const float*)d_in[5];
    const float* b2   = (const float*)d_in[6];
    const float* Wm1  = (const float*)d_in[7];
    const float* bm1  = (const float*)d_in[8];
    const float* Wm2  = (const float*)d_in[9];
    const float* bm2  = (const float*)d_in[10];
    float* out = (float*)d_out;

    // workspace layout (~66 MB); gcur and gt_sum adjacent for one memset
    char* ws = (char*)d_ws;
    char* p = ws;
    unsigned* bin   = (unsigned*)p;  p += (size_t)NBUCKETS * BIN_CAP * 4;   // 12.8 MB
    int*   csr      = (int*)p;       p += (size_t)NBUCKETS * BIN_CAP * 4;   // 12.8 MB (bucket regions)
    ushort* h1b     = (ushort*)p;    p += (size_t)N_NODES * 128 * 2;        // 25.6 MB
    ushort* xb      = (ushort*)p;    p += (size_t)N_NODES * 64 * 2;         // 12.8 MB
    int2*  rowse    = (int2*)p;      p += (size_t)N_NODES * 8;              // 800 KB
    float* dinv     = (float*)p;     p += (size_t)N_NODES * 4;
    int*   gcur     = (int*)p;       p += (size_t)NBUCKETS * 4;
    float* gt_sum   = (float*)p;     p += (size_t)N_GRAPHS * GRAPH_DIM * 4;
    float* gsum2    = (float*)p;     p += (size_t)N_GRAPHS * 128 * 4;

    // zero gcur + gt_sum in one shot (adjacent)
    hipMemsetAsync(gcur, 0, (size_t)NBUCKETS * 4 + (size_t)N_GRAPHS * GRAPH_DIM * 4, stream);

    // merged: edge binning + bf16 pack + graph stats
    k_binpack<<<NB_BIN + NB_PACK, 256, 0, stream>>>(src, dst, gcur, bin, x, batch, xb, gt_sum);

    // fused count+scan+fill per bucket
    k_build<<<NBUCKETS, 256, 0, stream>>>(gcur, bin, dinv, rowse, csr);

    // conv1 fused: z1 = A_hat * x64 (LDS) ; h1 = relu(z1 @ W1 + b1) (bf16)
    k_conv1<<<N_NODES / 8, 256, 0, stream>>>(csr, rowse, dinv, xb, W1, b1, h1b, gsum2);

    // conv2 pooled: gsum2[g] = sum_{node in g} (A_hat h1)[node]
    k_gather2<<<N_NODES / 8, 256, 0, stream>>>(csr, rowse, dinv,
                                               (const unsigned*)h1b, batch, gsum2);

    // final: gcnt + z = (gsum2/cnt) @ W2 + b2 ; MLP
    k_mlp<<<N_GRAPHS, 128, 0, stream>>>(gsum2, gt_sum, batch, W2, b2, Wm1, bm1, Wm2, bm2, out);
}

// Round 15
// 220.057 us; speedup vs baseline: 6.6288x; 1.0732x over previous
//
#include <hip/hip_runtime.h>
#include <hip/hip_bf16.h>

#define N_NODES 100000
#define N_EDGES 1600000
#define N_GRAPHS 512
#define NODE_DIM 64
#define GRAPH_DIM 16
#define HIDDEN 128
#define OUT_DIM 8

#define NBUCKETS 391      // ceil(N_NODES/256)
#define BIN_CAP 8192      // per-bucket bin + csr capacity (avg 4092)
#define EPB 4096          // edges per binning block
#define NB_BIN 391        // binplace blocks = ceil(N_EDGES/EPB)
#define NB_PACK 1563      // packstat blocks = ceil(N_NODES/64)

__device__ __forceinline__ float bflo(unsigned u) { return __uint_as_float(u << 16); }
__device__ __forceinline__ float bfhi(unsigned u) { return __uint_as_float(u & 0xffff0000u); }

// ---- merged phase A: blocks [0,NB_BIN) bin edges by dst>>8; blocks [NB_BIN,..) pack x + graph stats ----

__global__ __launch_bounds__(256) void k_binpack(const int* __restrict__ src,
                                                 const int* __restrict__ dst,
                                                 int* __restrict__ gcur,
                                                 unsigned* __restrict__ bin,
                                                 const float* __restrict__ x,
                                                 const int* __restrict__ batch,
                                                 ushort* __restrict__ xb,
                                                 float* __restrict__ gt_sum) {
    int t = threadIdx.x;
    if (blockIdx.x < NB_BIN) {
        __shared__ int cnt[NBUCKETS];
        __shared__ int base[NBUCKETS];
        for (int i = t; i < NBUCKETS; i += 256) cnt[i] = 0;
        __syncthreads();
        int e0 = blockIdx.x * EPB;
#pragma unroll
        for (int k = 0; k < EPB / 256; k++) {
            int e = e0 + k * 256 + t;
            if (e < N_EDGES) atomicAdd(&cnt[dst[e] >> 8], 1);
        }
        __syncthreads();
        for (int i = t; i < NBUCKETS; i += 256) {
            int c = cnt[i];
            base[i] = (c > 0) ? atomicAdd(&gcur[i], c) : 0;
            cnt[i] = 0;
        }
        __syncthreads();
#pragma unroll
        for (int k = 0; k < EPB / 256; k++) {
            int e = e0 + k * 256 + t;
            if (e < N_EDGES) {
                int d = dst[e];
                int b = d >> 8;
                int p = atomicAdd(&cnt[b], 1);
                bin[(size_t)b * BIN_CAP + base[b] + p] = ((unsigned)src[e] << 8) | (unsigned)(d & 255);
            }
        }
    } else {
        int i0 = (blockIdx.x - NB_BIN) * 64;
        for (int idx = t; idx < 64 * 32; idx += 256) {
            int node = i0 + (idx >> 5);
            if (node < N_NODES) {
                int c2 = idx & 31;
                float2 v = *(const float2*)&x[(size_t)node * 80 + c2 * 2];
                __hip_bfloat16 lo = __float2bfloat16(v.x);
                __hip_bfloat16 hi = __float2bfloat16(v.y);
                ushort2 pv = make_ushort2(*(ushort*)&lo, *(ushort*)&hi);
                ((ushort2*)xb)[(size_t)node * 32 + c2] = pv;
            }
        }
        int c = t & 15, sub = t >> 4;  // 16 subs x 16 channels
        int iend = min(i0 + 64, N_NODES);
        float acc = 0.0f;
        int g = -1;
        for (int i = i0 + sub; i < iend; i += 16) {
            int bi = batch[i];
            if (bi != g) {
                if (g >= 0) atomicAdd(&gt_sum[g * GRAPH_DIM + c], acc);
                acc = 0.0f; g = bi;
            }
            acc += x[(size_t)i * 80 + NODE_DIM + c];
        }
        if (g >= 0) atomicAdd(&gt_sum[g * GRAPH_DIM + c], acc);
    }
}

// ---- phase B (fused): count -> dinv + rowse -> CSR fill -> in-place rescale xb *= dinv ----

__global__ __launch_bounds__(256) void k_build(const int* __restrict__ gcur,
                                               const unsigned* __restrict__ bin,
                                               float* __restrict__ dinv,
                                               int2* __restrict__ rowse,
                                               int* __restrict__ csr,
                                               ushort* __restrict__ xb) {
    __shared__ int cnt[256];
    __shared__ int sc[256];
    __shared__ int rsl[256];
    __shared__ float dl[256];
    int b = blockIdx.x, t = threadIdx.x;
    cnt[t] = 0;
    __syncthreads();
    int n = gcur[b];
    const unsigned* seg = bin + (size_t)b * BIN_CAP;
    for (int i = t; i < n; i += 256) atomicAdd(&cnt[seg[i] & 255u], 1);
    __syncthreads();
    int deg = cnt[t];
    sc[t] = deg;
    __syncthreads();
    for (int o = 1; o < 256; o <<= 1) {
        int u = (t >= o) ? sc[t - o] : 0;
        __syncthreads();
        sc[t] += u;
        __syncthreads();
    }
    int rs = b * BIN_CAP + sc[t] - deg;   // bucket-region base, exclusive prefix
    int node = b * 256 + t;
    float dv = rsqrtf((float)deg + 1.0f);
    if (node < N_NODES) {
        dinv[node] = dv;
        rowse[node] = make_int2(rs, rs + deg);
    }
    rsl[t] = rs;
    dl[t] = dv;
    cnt[t] = 0;
    __syncthreads();
    for (int i = t; i < n; i += 256) {
        unsigned e = seg[i];
        int dlidx = (int)(e & 255u);
        csr[rsl[dlidx] + atomicAdd(&cnt[dlidx], 1)] = (int)(e >> 8);
    }
    __syncthreads();
    // in-place rescale: xs = bf16(dinv * xb)
    unsigned* xw = (unsigned*)xb;
    for (int idx = t; idx < 256 * 32; idx += 256) {
        int nl = idx >> 5;
        int nn = b * 256 + nl;
        if (nn < N_NODES) {
            int c2 = idx & 31;
            unsigned u = xw[(size_t)nn * 32 + c2];
            float d = dl[nl];
            float lo = bflo(u) * d;
            float hi = bfhi(u) * d;
            __hip_bfloat16 l2 = __float2bfloat16(lo);
            __hip_bfloat16 h2 = __float2bfloat16(hi);
            xw[(size_t)nn * 32 + c2] = ((unsigned)(*(ushort*)&h2) << 16) | (unsigned)(*(ushort*)&l2);
        }
    }
}

// ---- fused conv1: weightless unroll-8 cascade gather + full-block GEMM; zeroes gsum2 ----
// z[i] = dinv[i] * (sum_e xs[src_e] + xs[i]);  h_s = bf16(dinv * relu(z @ W1 + b1))

#define LDX(s_) __uint_as_float((unsigned)xb[(size_t)(s_)*64 + lane] << 16)

#define C1_E8(kX, aX0, aX1, aX2, aX3) {                                              \
    int s0 = csr[kX],     s1 = csr[kX + 1], s2 = csr[kX + 2], s3 = csr[kX + 3];      \
    int s4 = csr[kX + 4], s5 = csr[kX + 5], s6 = csr[kX + 6], s7 = csr[kX + 7];      \
    float v0 = LDX(s0), v1 = LDX(s1), v2 = LDX(s2), v3 = LDX(s3);                    \
    float v4 = LDX(s4), v5 = LDX(s5), v6 = LDX(s6), v7 = LDX(s7);                    \
    aX0 += v0; aX1 += v1; aX2 += v2; aX3 += v3;                                      \
    aX0 += v4; aX1 += v5; aX2 += v6; aX3 += v7; }

#define C1_E4(kX, aX0, aX1, aX2, aX3) {                                              \
    int s0 = csr[kX], s1 = csr[kX + 1], s2 = csr[kX + 2], s3 = csr[kX + 3];          \
    float v0 = LDX(s0), v1 = LDX(s1), v2 = LDX(s2), v3 = LDX(s3);                    \
    aX0 += v0; aX1 += v1; aX2 += v2; aX3 += v3; }

#define C1_E1(kX, aX0) { int s0 = csr[kX]; aX0 += LDX(s0); }

__global__ __launch_bounds__(256) void k_conv1(const int* __restrict__ csr,
                                               const int2* __restrict__ rowse,
                                               const float* __restrict__ dinv,
                                               const ushort* __restrict__ xb,
                                               const float* __restrict__ W,
                                               const float* __restrict__ bias,
                                               ushort* __restrict__ C,
                                               float* __restrict__ gsum2) {
    __shared__ float zs[8][64];
    int t = threadIdx.x;
    if (blockIdx.x < 256) gsum2[blockIdx.x * 256 + t] = 0.0f;
    int w = t >> 6, lane = t & 63;
    int nA = blockIdx.x * 8 + w * 2;
    int nB = nA + 1;
    int2 seA = rowse[nA];
    int2 seB = rowse[nB];
    int kA = seA.x, reA = seA.y;
    int kB = seB.x, reB = seB.y;
    float dA = dinv[nA], dB = dinv[nB];
    float aA0 = 0.f, aA1 = 0.f, aA2 = 0.f, aA3 = 0.f;
    float aB0 = 0.f, aB1 = 0.f, aB2 = 0.f, aB3 = 0.f;
    while (kA + 8 <= reA && kB + 8 <= reB) {
        C1_E8(kA, aA0, aA1, aA2, aA3)
        C1_E8(kB, aB0, aB1, aB2, aB3)
        kA += 8; kB += 8;
    }
    while (kA + 8 <= reA) { C1_E8(kA, aA0, aA1, aA2, aA3) kA += 8; }
    while (kB + 8 <= reB) { C1_E8(kB, aB0, aB1, aB2, aB3) kB += 8; }
    while (kA + 4 <= reA && kB + 4 <= reB) {
        C1_E4(kA, aA0, aA1, aA2, aA3)
        C1_E4(kB, aB0, aB1, aB2, aB3)
        kA += 4; kB += 4;
    }
    while (kA + 4 <= reA) { C1_E4(kA, aA0, aA1, aA2, aA3) kA += 4; }
    while (kB + 4 <= reB) { C1_E4(kB, aB0, aB1, aB2, aB3) kB += 4; }
    while (kA < reA && kB < reB) { C1_E1(kA, aA0) C1_E1(kB, aB0) kA++; kB++; }
    while (kA < reA) { C1_E1(kA, aA0) kA++; }
    while (kB < reB) { C1_E1(kB, aB0) kB++; }
    zs[w * 2][lane]     = dA * (aA0 + aA1 + aA2 + aA3 + LDX(nA));
    zs[w * 2 + 1][lane] = dB * (aB0 + aB1 + aB2 + aB3 + LDX(nB));
    __syncthreads();
    // GEMM phase: all 256 threads; j = t&127, half hf computes rows hf*4 .. hf*4+3
    {
        int j = t & 127;
        int hf = t >> 7;
        float acc[4];
#pragma unroll
        for (int m = 0; m < 4; m++) acc[m] = 0.0f;
        for (int k = 0; k < 64; k++) {
            float wk = W[k * 128 + j];
#pragma unroll
            for (int m = 0; m < 4; m++) acc[m] += zs[hf * 4 + m][k] * wk;
        }
        float b = bias[j];
        size_t row0 = (size_t)blockIdx.x * 8 + hf * 4;
#pragma unroll
        for (int m = 0; m < 4; m++) {
            float v = fmaxf(acc[m] + b, 0.0f) * dinv[row0 + m];
            __hip_bfloat16 hv = __float2bfloat16(v);
            C[(row0 + m) * 128 + j] = *(ushort*)&hv;
        }
    }
}

// ---- gather2: weightless unroll-8 cascade (hs bf16, 2 nodes/wave, 2ch/lane) + fused mean-pool ----
// pool-row[i] = dinv[i] * (sum_e hs[src_e] + hs[i])

#define ADD2(acc_, u_) { acc_.x += bflo(u_); acc_.y += bfhi(u_); }

#define G2_E8(kX, aX0, aX1, aX2, aX3) {                                              \
    int s0 = csr[kX],     s1 = csr[kX + 1], s2 = csr[kX + 2], s3 = csr[kX + 3];      \
    int s4 = csr[kX + 4], s5 = csr[kX + 5], s6 = csr[kX + 6], s7 = csr[kX + 7];      \
    unsigned u0 = h[(size_t)s0 * 64 + lane], u1 = h[(size_t)s1 * 64 + lane];         \
    unsigned u2 = h[(size_t)s2 * 64 + lane], u3 = h[(size_t)s3 * 64 + lane];         \
    unsigned u4 = h[(size_t)s4 * 64 + lane], u5 = h[(size_t)s5 * 64 + lane];         \
    unsigned u6 = h[(size_t)s6 * 64 + lane], u7 = h[(size_t)s7 * 64 + lane];         \
    ADD2(aX0, u0) ADD2(aX1, u1) ADD2(aX2, u2) ADD2(aX3, u3)                          \
    ADD2(aX0, u4) ADD2(aX1, u5) ADD2(aX2, u6) ADD2(aX3, u7) }

#define G2_E4(kX, aX0, aX1, aX2, aX3) {                                              \
    int s0 = csr[kX], s1 = csr[kX + 1], s2 = csr[kX + 2], s3 = csr[kX + 3];          \
    unsigned u0 = h[(size_t)s0 * 64 + lane], u1 = h[(size_t)s1 * 64 + lane];         \
    unsigned u2 = h[(size_t)s2 * 64 + lane], u3 = h[(size_t)s3 * 64 + lane];         \
    ADD2(aX0, u0) ADD2(aX1, u1) ADD2(aX2, u2) ADD2(aX3, u3) }

#define G2_E1(kX, aX0) {                                                             \
    int s0 = csr[kX];                                                                \
    unsigned u0 = h[(size_t)s0 * 64 + lane];                                         \
    ADD2(aX0, u0) }

__global__ __launch_bounds__(256) void k_gather2(const int* __restrict__ csr,
                                                 const int2* __restrict__ rowse,
                                                 const float* __restrict__ dinv,
                                                 const unsigned* __restrict__ h,
                                                 const int* __restrict__ batch,
                                                 float* __restrict__ gsum2) {
    __shared__ float2 red[8][64];
    int w = threadIdx.x >> 6, lane = threadIdx.x & 63;
    int nA = blockIdx.x * 8 + w * 2;
    int nB = nA + 1;
    int2 seA = rowse[nA];
    int2 seB = rowse[nB];
    int kA = seA.x, reA = seA.y;
    int kB = seB.x, reB = seB.y;
    float dA = dinv[nA], dB = dinv[nB];
    float2 aA0 = {0.f,0.f}, aA1 = {0.f,0.f}, aA2 = {0.f,0.f}, aA3 = {0.f,0.f};
    float2 aB0 = {0.f,0.f}, aB1 = {0.f,0.f}, aB2 = {0.f,0.f}, aB3 = {0.f,0.f};
    while (kA + 8 <= reA && kB + 8 <= reB) {
        G2_E8(kA, aA0, aA1, aA2, aA3)
        G2_E8(kB, aB0, aB1, aB2, aB3)
        kA += 8; kB += 8;
    }
    while (kA + 8 <= reA) { G2_E8(kA, aA0, aA1, aA2, aA3) kA += 8; }
    while (kB + 8 <= reB) { G2_E8(kB, aB0, aB1, aB2, aB3) kB += 8; }
    while (kA + 4 <= reA && kB + 4 <= reB) {
        G2_E4(kA, aA0, aA1, aA2, aA3)
        G2_E4(kB, aB0, aB1, aB2, aB3)
        kA += 4; kB += 4;
    }
    while (kA + 4 <= reA) { G2_E4(kA, aA0, aA1, aA2, aA3) kA += 4; }
    while (kB + 4 <= reB) { G2_E4(kB, aB0, aB1, aB2, aB3) kB += 4; }
    while (kA < reA && kB < reB) { G2_E1(kA, aA0) G2_E1(kB, aB0) kA++; kB++; }
    while (kA < reA) { G2_E1(kA, aA0) kA++; }
    while (kB < reB) { G2_E1(kB, aB0) kB++; }
    unsigned usA = h[(size_t)nA * 64 + lane];
    unsigned usB = h[(size_t)nB * 64 + lane];
    float2 rA, rB;
    rA.x = dA * (aA0.x + aA1.x + aA2.x + aA3.x + bflo(usA));
    rA.y = dA * (aA0.y + aA1.y + aA2.y + aA3.y + bfhi(usA));
    rB.x = dB * (aB0.x + aB1.x + aB2.x + aB3.x + bflo(usB));
    rB.y = dB * (aB0.y + aB1.y + aB2.y + aB3.y + bfhi(usB));
    red[w * 2][lane] = rA;
    red[w * 2 + 1][lane] = rB;
    __syncthreads();
    int g0 = batch[blockIdx.x * 8];
    int g7 = batch[blockIdx.x * 8 + 7];
    if (g0 == g7) {
        if (w == 0) {
            float sx = 0.f, sy = 0.f;
#pragma unroll
            for (int q = 0; q < 8; q++) { sx += red[q][lane].x; sy += red[q][lane].y; }
            atomicAdd(&gsum2[g0 * 128 + 2 * lane], sx);
            atomicAdd(&gsum2[g0 * 128 + 2 * lane + 1], sy);
        }
    } else {
        int gA = batch[nA], gB = batch[nB];
        atomicAdd(&gsum2[gA * 128 + 2 * lane], rA.x);
        atomicAdd(&gsum2[gA * 128 + 2 * lane + 1], rA.y);
        atomicAdd(&gsum2[gB * 128 + 2 * lane], rB.x);
        atomicAdd(&gsum2[gB * 128 + 2 * lane + 1], rB.y);
    }
}

// ---------------- final: gcnt (binary search) + z = mean2 @ W2 + b2 ; MLP ----------------

__global__ __launch_bounds__(128) void k_mlp(const float* __restrict__ gsum2,
                                             const float* __restrict__ gt_sum,
                                             const int* __restrict__ batch,
                                             const float* __restrict__ W2,
                                             const float* __restrict__ b2,
                                             const float* __restrict__ Wm1,
                                             const float* __restrict__ bm1,
                                             const float* __restrict__ Wm2,
                                             const float* __restrict__ bm2,
                                             float* __restrict__ out) {
    __shared__ float srow[HIDDEN];
    __shared__ float g144[HIDDEN + GRAPH_DIM];
    __shared__ float sm[HIDDEN];
    __shared__ int cnt_sh;
    int b = blockIdx.x;
    int j = threadIdx.x;  // 0..127
    float raw = gsum2[b * 128 + j];
    float gtraw = (j < GRAPH_DIM) ? gt_sum[b * GRAPH_DIM + j] : 0.0f;
    if (j == 0) {
        int lo = 0, hi = N_NODES;
        while (lo < hi) { int m = (lo + hi) >> 1; if (batch[m] < b) lo = m + 1; else hi = m; }
        int a = lo;
        lo = 0; hi = N_NODES;
        while (lo < hi) { int m = (lo + hi) >> 1; if (batch[m] < b + 1) lo = m + 1; else hi = m; }
        cnt_sh = lo - a;
    }
    __syncthreads();
    float inv = 1.0f / fmaxf((float)cnt_sh, 1.0f);
    srow[j] = raw * inv;
    if (j < GRAPH_DIM) g144[128 + j] = gtraw * inv;
    __syncthreads();
    float z = b2[j];
    for (int k = 0; k < 128; k++) z += srow[k] * W2[k * 128 + j];
    g144[j] = z;
    __syncthreads();
    float acc = bm1[j];
    for (int k = 0; k < HIDDEN + GRAPH_DIM; k++) acc += g144[k] * Wm1[k * 128 + j];
    sm[j] = fmaxf(acc, 0.0f);
    __syncthreads();
    if (j < OUT_DIM) {
        float o = bm2[j];
        for (int k = 0; k < 128; k++) o += sm[k] * Wm2[k * OUT_DIM + j];
        out[b * OUT_DIM + j] = o;
    }
}

extern "C" void kernel_launch(void* const* d_in, const int* in_sizes, int n_in,
                              void* d_out, int out_size, void* d_ws, size_t ws_size,
                              hipStream_t stream) {
    const float* x    = (const float*)d_in[0];
    const int*   edge = (const int*)d_in[1];
    const int*   src  = edge;
    const int*   dst  = edge + N_EDGES;
    const int*   batch= (const int*)d_in[2];
    const float* W1   = (const float*)d_in[3];
    const float* b1   = (const float*)d_in[4];
    const float* W2   = (const float*)d_in[5];
    const float* b2   = (const float*)d_in[6];
    const float* Wm1  = (const float*)d_in[7];
    const float* bm1  = (const float*)d_in[8];
    const float* Wm2  = (const float*)d_in[9];
    const float* bm2  = (const float*)d_in[10];
    float* out = (float*)d_out;

    // workspace layout (~66 MB); gcur and gt_sum adjacent for one memset
    char* ws = (char*)d_ws;
    char* p = ws;
    unsigned* bin   = (unsigned*)p;  p += (size_t)NBUCKETS * BIN_CAP * 4;   // 12.8 MB
    int*   csr      = (int*)p;       p += (size_t)NBUCKETS * BIN_CAP * 4;   // 12.8 MB (bucket regions)
    ushort* h1b     = (ushort*)p;    p += (size_t)N_NODES * 128 * 2;        // 25.6 MB (hs = dinv*h1)
    ushort* xb      = (ushort*)p;    p += (size_t)N_NODES * 64 * 2;         // 12.8 MB (xs = dinv*x64)
    int2*  rowse    = (int2*)p;      p += (size_t)N_NODES * 8;              // 800 KB
    float* dinv     = (float*)p;     p += (size_t)N_NODES * 4;
    int*   gcur     = (int*)p;       p += (size_t)NBUCKETS * 4;
    float* gt_sum   = (float*)p;     p += (size_t)N_GRAPHS * GRAPH_DIM * 4;
    float* gsum2    = (float*)p;     p += (size_t)N_GRAPHS * 128 * 4;

    // zero gcur + gt_sum in one shot (adjacent)
    hipMemsetAsync(gcur, 0, (size_t)NBUCKETS * 4 + (size_t)N_GRAPHS * GRAPH_DIM * 4, stream);

    // merged: edge binning + bf16 pack + graph stats
    k_binpack<<<NB_BIN + NB_PACK, 256, 0, stream>>>(src, dst, gcur, bin, x, batch, xb, gt_sum);

    // fused count+scan+fill per bucket, then xs = dinv * xb in place
    k_build<<<NBUCKETS, 256, 0, stream>>>(gcur, bin, dinv, rowse, csr, xb);

    // conv1 fused: z1 = dinv*(sum xs) ; hs = dinv*relu(z1 @ W1 + b1) (bf16)
    k_conv1<<<N_NODES / 8, 256, 0, stream>>>(csr, rowse, dinv, xb, W1, b1, h1b, gsum2);

    // conv2 pooled: gsum2[g] += dinv[i]*(sum_e hs[src] + hs[i])
    k_gather2<<<N_NODES / 8, 256, 0, stream>>>(csr, rowse, dinv,
                                               (const unsigned*)h1b, batch, gsum2);

    // final: gcnt + z = (gsum2/cnt) @ W2 + b2 ; MLP
    k_mlp<<<N_GRAPHS, 128, 0, stream>>>(gsum2, gt_sum, batch, W2, b2, Wm1, bm1, Wm2, bm2, out);
}